// Round 1
// baseline (4183.516 us; speedup 1.0000x reference)
//
#include <hip/hip_runtime.h>
#include <math.h>

#define HH 64
#define WW 64
#define NIMG 4
#define CIN 512
#define AA 9
#define HWA (HH*WW*AA)          // 36864
#define PRE_NMS 6000
#define POST_NMS 300
#define NEGV (-1e10f)
#define NEGK 0xD01502F9u        // descending-order key of -1e10f

#define OFF1 589824             // rpn_scores
#define OFF2 884736             // rois
#define OFF3 889536             // roi_indices
#define OFF4 890736             // anchors

typedef unsigned int u32;
typedef unsigned long long u64;

// ---------------- W transpose: W[co][ci][tap] -> Wt[ci*9+tap][co] ----------------
__global__ __launch_bounds__(256) void k_transpose(const float* __restrict__ Wsrc,
                                                   float* __restrict__ Wt)
{
    __shared__ float tile[64][65];
    int rt0 = blockIdx.x * 64;   // ci*9+tap tile (4608/64 = 72)
    int co0 = blockIdx.y * 64;   // co tile (512/64 = 8)
    int t = threadIdx.x;
    #pragma unroll
    for (int l = 0; l < 16; ++l) {
        int i = l * 256 + t;
        int rr = i & 63, cc = i >> 6;
        tile[cc][rr] = Wsrc[(size_t)(co0 + cc) * 4608 + rt0 + rr];
    }
    __syncthreads();
    #pragma unroll
    for (int l = 0; l < 16; ++l) {
        int i = l * 256 + t;
        int cc = i & 63, rr = i >> 6;
        Wt[(size_t)(rt0 + rr) * 512 + co0 + cc] = tile[cc][rr];
    }
}

// ---------------- conv 3x3 (pad 1) + bias + ReLU ----------------
// Block: 256 threads, tile = 64 cout x (2 rows x 64 cols). Grid (8, 32, 4).
__global__ __launch_bounds__(256, 2) void k_conv3x3(const float* __restrict__ x,
                                                    const float* __restrict__ wt,
                                                    const float* __restrict__ bias,
                                                    float* __restrict__ mid)
{
    __shared__ float sW[72 * 64];     // [ci*9+tap][co]
    __shared__ float sI[8][4][68];    // [ci][row y0-1..y0+2][col -1..66]
    const int t = threadIdx.x;
    const int n = blockIdx.z, co0 = blockIdx.x * 64, y0 = blockIdx.y * 2;
    const int tx = t & 15, ty = t >> 4;
    const int x0 = tx * 4;

    float acc[4][2][4];
    #pragma unroll
    for (int c = 0; c < 4; ++c)
        #pragma unroll
        for (int r = 0; r < 2; ++r)
            #pragma unroll
            for (int j = 0; j < 4; ++j) acc[c][r][j] = 0.f;

    for (int ci0 = 0; ci0 < 512; ci0 += 8) {
        __syncthreads();
        // stage weights: 4608 floats, coalesced from transposed layout
        #pragma unroll
        for (int l = 0; l < 18; ++l) {
            int i = l * 256 + t;
            int tc = i >> 6, co = i & 63;
            sW[i] = wt[(size_t)(ci0 * 9 + tc) * 512 + co0 + co];
        }
        // stage input rows y0-1..y0+2 for 8 channels
        #pragma unroll
        for (int l = 0; l < 8; ++l) {
            int i = l * 256 + t;
            int col = i & 63, r = (i >> 6) & 3, ci = i >> 8;
            int gy = y0 + r - 1;
            float v = 0.f;
            if (gy >= 0 && gy < HH)
                v = x[((size_t)(n * CIN + ci0 + ci) * HH + gy) * WW + col];
            sI[ci][r][col + 1] = v;
        }
        if (t < 32) {
            int ci = t >> 2, r = t & 3;
            sI[ci][r][0] = 0.f; sI[ci][r][65] = 0.f; sI[ci][r][66] = 0.f; sI[ci][r][67] = 0.f;
        }
        __syncthreads();

        #pragma unroll
        for (int ci = 0; ci < 8; ++ci) {
            float row[4][6];
            #pragma unroll
            for (int r = 0; r < 4; ++r)
                #pragma unroll
                for (int j = 0; j < 6; ++j) row[r][j] = sI[ci][r][x0 + j];
            #pragma unroll
            for (int ky = 0; ky < 3; ++ky) {
                float wv[3][4];
                #pragma unroll
                for (int kx = 0; kx < 3; ++kx)
                    #pragma unroll
                    for (int c = 0; c < 4; ++c)
                        wv[kx][c] = sW[(ci * 9 + ky * 3 + kx) * 64 + ty * 4 + c];
                #pragma unroll
                for (int kx = 0; kx < 3; ++kx)
                    #pragma unroll
                    for (int c = 0; c < 4; ++c)
                        #pragma unroll
                        for (int j = 0; j < 4; ++j) {
                            acc[c][0][j] += wv[kx][c] * row[ky][kx + j];
                            acc[c][1][j] += wv[kx][c] * row[ky + 1][kx + j];
                        }
            }
        }
    }
    // epilogue: bias + relu
    #pragma unroll
    for (int c = 0; c < 4; ++c) {
        float bv = bias[co0 + ty * 4 + c];
        #pragma unroll
        for (int r = 0; r < 2; ++r) {
            #pragma unroll
            for (int j = 0; j < 4; ++j) {
                float v = acc[c][r][j] + bv;
                mid[((size_t)(n * 512 + co0 + ty * 4 + c) * HH + y0 + r) * WW + x0 + j] =
                    v > 0.f ? v : 0.f;
            }
        }
    }
}

// ---------------- 1x1 heads + box decode + score keys ----------------
__global__ __launch_bounds__(256) void k_heads(const float* __restrict__ mid,
                                               const float* __restrict__ Wsc,
                                               const float* __restrict__ bsc,
                                               const float* __restrict__ Wlc,
                                               const float* __restrict__ blc,
                                               const int* __restrict__ ph,
                                               const int* __restrict__ pw,
                                               float* __restrict__ out,
                                               float* __restrict__ boxes,
                                               u32* __restrict__ key)
{
    int p = blockIdx.x * 256 + threadIdx.x;   // 0..16383
    int n = p >> 12, pi = p & 4095;
    int y = pi >> 6, xq = pi & 63;

    float accS[18], accL[36];
    #pragma unroll
    for (int c = 0; c < 18; ++c) accS[c] = bsc[c];
    #pragma unroll
    for (int c = 0; c < 36; ++c) accL[c] = blc[c];

    const float* mbase = mid + (size_t)n * (512 * 4096) + pi;
    #pragma unroll 8
    for (int ci = 0; ci < 512; ++ci) {
        float m = mbase[(size_t)ci * 4096];
        #pragma unroll
        for (int c = 0; c < 18; ++c) accS[c] += Wsc[c * 512 + ci] * m;
        #pragma unroll
        for (int c = 0; c < 36; ++c) accL[c] += Wlc[c * 512 + ci] * m;
    }

    float* o0 = out + (size_t)n * 147456;
    float* o1 = out + OFF1 + (size_t)n * 73728;
    float IHf = (float)(*ph), IWf = (float)(*pw);

    #pragma unroll
    for (int a = 0; a < 9; ++a) {
        #pragma unroll
        for (int j = 0; j < 2; ++j) o1[(pi * 9 + a) * 2 + j] = accS[a * 2 + j];
        #pragma unroll
        for (int j = 0; j < 4; ++j) o0[(pi * 9 + a) * 4 + j] = accL[a * 4 + j];

        // softmax fg (max-subtracted like jax.nn.softmax)
        float s0 = accS[a * 2], s1 = accS[a * 2 + 1];
        float mm = fmaxf(s0, s1);
        float e0 = expf(s0 - mm), e1 = expf(s1 - mm);
        float fg = e1 / (e0 + e1);

        // anchor (base in f64 like numpy, then f32 add of exact shift)
        int ri = a / 3, si = a - ri * 3;
        double s = (double)(8 << si);
        double rr = (ri == 0) ? 0.5 : ((ri == 1) ? 1.0 : 2.0);
        double hh = 16.0 * s * sqrt(rr);
        double wd = 16.0 * s * sqrt(1.0 / rr);
        float a0 = (float)(8.0 - hh * 0.5) + (float)(y * 16);
        float a1 = (float)(8.0 - wd * 0.5) + (float)(xq * 16);
        float a2 = (float)(8.0 + hh * 0.5) + (float)(y * 16);
        float a3 = (float)(8.0 + wd * 0.5) + (float)(xq * 16);

        // loc2bbox
        float h = a2 - a0, w = a3 - a1;
        float cy = a0 + 0.5f * h, cx = a1 + 0.5f * w;
        float dy = accL[a * 4 + 0], dx = accL[a * 4 + 1];
        float dh = accL[a * 4 + 2], dw = accL[a * 4 + 3];
        float ncy = dy * h + cy, ncx = dx * w + cx;
        float nh = expf(dh) * h, nw = expf(dw) * w;
        float b0 = fminf(fmaxf(ncy - 0.5f * nh, 0.f), IHf);
        float b1 = fminf(fmaxf(ncx - 0.5f * nw, 0.f), IWf);
        float b2 = fminf(fmaxf(ncy + 0.5f * nh, 0.f), IHf);
        float b3 = fminf(fmaxf(ncx + 0.5f * nw, 0.f), IWf);

        bool ok = (b2 - b0 >= 16.0f) && (b3 - b1 >= 16.0f);
        float sc = ok ? fg : NEGV;

        int gi = n * HWA + pi * 9 + a;
        float4 bx = make_float4(b0, b1, b2, b3);
        ((float4*)boxes)[gi] = bx;
        u32 u = __float_as_uint(sc);
        u32 kasc = (u & 0x80000000u) ? ~u : (u | 0x80000000u);
        key[gi] = ~kasc;   // ascending key == descending score
    }
}

// ---------------- anchors out + roi_indices + zero rois ----------------
__global__ void k_misc(float* __restrict__ out)
{
    int i = blockIdx.x * 256 + threadIdx.x;
    if (i < 4800) out[OFF2 + i] = 0.f;
    if (i < 1200) out[OFF3 + i] = (float)(i / 300);
    if (i < HWA) {
        int pi = i / 9, a = i - pi * 9;
        int y = pi >> 6, xq = pi & 63;
        int ri = a / 3, si = a - ri * 3;
        double s = (double)(8 << si);
        double rr = (ri == 0) ? 0.5 : ((ri == 1) ? 1.0 : 2.0);
        double hh = 16.0 * s * sqrt(rr);
        double wd = 16.0 * s * sqrt(1.0 / rr);
        out[OFF4 + i * 4 + 0] = (float)(8.0 - hh * 0.5) + (float)(y * 16);
        out[OFF4 + i * 4 + 1] = (float)(8.0 - wd * 0.5) + (float)(xq * 16);
        out[OFF4 + i * 4 + 2] = (float)(8.0 + hh * 0.5) + (float)(y * 16);
        out[OFF4 + i * 4 + 3] = (float)(8.0 + wd * 0.5) + (float)(xq * 16);
    }
}

// ---------------- exact rank-6000 radix select + compact ----------------
__global__ __launch_bounds__(1024) void k_select(const u32* __restrict__ key,
                                                 u64* __restrict__ cmp,
                                                 int* __restrict__ nvalid)
{
    __shared__ int hist[256];
    __shared__ u32 sPref;
    __shared__ int sR;
    __shared__ int cLess, cEq, cVal;
    int n = blockIdx.x, t = threadIdx.x;
    const u32* k0 = key + (size_t)n * HWA;

    u32 pref = 0, mask = 0;
    int R = PRE_NMS;
    for (int pass = 0; pass < 4; ++pass) {
        int shift = 24 - pass * 8;
        if (t < 256) hist[t] = 0;
        __syncthreads();
        for (int i = t; i < HWA; i += 1024) {
            u32 k = k0[i];
            if ((k & mask) == pref) atomicAdd(&hist[(k >> shift) & 255], 1);
        }
        __syncthreads();
        if (t == 0) {
            int cum = 0;
            for (int b = 0; b < 256; ++b) {
                int c = hist[b];
                if (cum + c >= R) { sPref = pref | ((u32)b << shift); sR = R - cum; break; }
                cum += c;
            }
        }
        __syncthreads();
        pref = sPref; R = sR; mask |= (0xFFu << shift);
        __syncthreads();
    }
    u32 T = pref;   // exact 6000th smallest key
    if (t == 0) { cLess = 0; cEq = 0; cVal = 0; }
    __syncthreads();
    for (int i = t; i < HWA; i += 1024) {
        u32 k = k0[i];
        if (k < NEGK) atomicAdd(&cVal, 1);
        if (k < T) {
            int p = atomicAdd(&cLess, 1);
            cmp[(size_t)n * 8192 + p] = ((u64)k << 32) | (u32)i;
        } else if (k == T) {
            int p = atomicAdd(&cEq, 1);
            if (p < R) cmp[(size_t)n * 8192 + (PRE_NMS - 1 - p)] = ((u64)k << 32) | (u32)i;
        }
    }
    for (int i = PRE_NMS + t; i < 8192; i += 1024) cmp[(size_t)n * 8192 + i] = ~0ull;
    __syncthreads();
    if (t == 0) nvalid[n] = cVal < PRE_NMS ? cVal : PRE_NMS;
}

// ---------------- bitonic sort of 8192 (key<<32|idx) in LDS ----------------
__global__ __launch_bounds__(1024) void k_sort(const u64* __restrict__ cmp,
                                               const float* __restrict__ boxes,
                                               float* __restrict__ boxesS)
{
    __shared__ u64 sK[8192];   // exactly 64 KiB
    int n = blockIdx.x, t = threadIdx.x;
    for (int i = t; i < 8192; i += 1024) sK[i] = cmp[(size_t)n * 8192 + i];
    for (unsigned k = 2; k <= 8192; k <<= 1) {
        for (unsigned j = k >> 1; j > 0; j >>= 1) {
            __syncthreads();
            #pragma unroll
            for (int v = 0; v < 8; ++v) {
                int i = v * 1024 + t;
                int ixj = i ^ (int)j;
                if (ixj > i) {
                    u64 a = sK[i], b = sK[ixj];
                    bool up = ((i & (int)k) == 0);
                    if (up ? (a > b) : (a < b)) { sK[i] = b; sK[ixj] = a; }
                }
            }
        }
    }
    __syncthreads();
    const float4* bsrc = (const float4*)boxes + (size_t)n * HWA;
    float4* bdst = (float4*)boxesS + (size_t)n * PRE_NMS;
    for (int i = t; i < PRE_NMS; i += 1024) {
        u32 idx = (u32)(sK[i] & 0xFFFFFFFFu);
        bdst[i] = bsrc[idx];
    }
}

// ---------------- greedy NMS (matches lax.scan argmax semantics) ----------------
__global__ __launch_bounds__(256) void k_nms(const float* __restrict__ boxesS,
                                             const int* __restrict__ nvalid,
                                             float* __restrict__ rois)
{
    __shared__ unsigned char sup[PRE_NMS];
    __shared__ int sMin, sPtr, sCnt;
    int n = blockIdx.x, t = threadIdx.x;
    const float4* B = (const float4*)boxesS + (size_t)n * PRE_NMS;
    int nv = nvalid[n];
    for (int i = t; i < PRE_NMS; i += 256) sup[i] = 0;
    if (t == 0) { sPtr = 0; sCnt = 0; }
    __syncthreads();

    while (true) {
        int sel = -1;
        int ptr = sPtr;
        while (sel < 0 && ptr < nv) {
            if (t == 0) sMin = 0x7fffffff;
            __syncthreads();
            int idx = ptr + t;
            if (idx < nv && !sup[idx]) atomicMin(&sMin, idx);
            __syncthreads();
            if (sMin != 0x7fffffff) sel = sMin; else ptr += 256;
        }
        if (sel < 0) break;

        float4 bb = B[sel];
        if (t == 0) {
            int cnt = sCnt;
            float* orow = rois + (size_t)(n * POST_NMS + cnt) * 4;
            orow[0] = bb.x; orow[1] = bb.y; orow[2] = bb.z; orow[3] = bb.w;
            sPtr = sel + 1;
            sCnt = cnt + 1;
        }
        float area1 = (bb.z - bb.x) * (bb.w - bb.y);
        for (int jj = sel + 1 + t; jj < nv; jj += 256) {
            if (!sup[jj]) {
                float4 o = B[jj];
                float ty_ = fmaxf(bb.x, o.x), tx_ = fmaxf(bb.y, o.y);
                float by_ = fminf(bb.z, o.z), bx_ = fminf(bb.w, o.w);
                float inter = fmaxf(by_ - ty_, 0.f) * fmaxf(bx_ - tx_, 0.f);
                float area2 = (o.z - o.x) * (o.w - o.y);
                float iou = inter / (area1 + area2 - inter + 1e-9f);
                if (iou > 0.7f) sup[jj] = 1;
            }
        }
        __syncthreads();
        if (sCnt >= POST_NMS) break;
    }
}

extern "C" void kernel_launch(void* const* d_in, const int* in_sizes, int n_in,
                              void* d_out, int out_size, void* d_ws, size_t ws_size,
                              hipStream_t stream)
{
    const float* x  = (const float*)d_in[0];
    const float* W1 = (const float*)d_in[1];
    const float* b1 = (const float*)d_in[2];
    const float* Ws = (const float*)d_in[3];
    const float* bs = (const float*)d_in[4];
    const float* Wl = (const float*)d_in[5];
    const float* bl = (const float*)d_in[6];
    const int* ih   = (const int*)d_in[7];
    const int* iw   = (const int*)d_in[8];
    float* out = (float*)d_out;
    char* ws = (char*)d_ws;

    float* Wt     = (float*)(ws);                 //  9,437,184 B
    float* mid    = (float*)(ws + 9437184);       // 33,554,432 B
    float* boxes  = (float*)(ws + 42991616);      //  2,359,296 B
    u32*   key    = (u32*)  (ws + 45350912);      //    589,824 B
    u64*   cmp    = (u64*)  (ws + 45940736);      //    262,144 B
    float* boxesS = (float*)(ws + 46202880);      //    384,000 B
    int*   nval   = (int*)  (ws + 46586880);      //         16 B

    k_transpose<<<dim3(72, 8), 256, 0, stream>>>(W1, Wt);
    k_conv3x3<<<dim3(8, 32, 4), 256, 0, stream>>>(x, Wt, b1, mid);
    k_heads<<<64, 256, 0, stream>>>(mid, Ws, bs, Wl, bl, ih, iw, out, boxes, key);
    k_misc<<<144, 256, 0, stream>>>(out);
    k_select<<<4, 1024, 0, stream>>>(key, cmp, nval);
    k_sort<<<4, 1024, 0, stream>>>(cmp, boxes, boxesS);
    k_nms<<<4, 256, 0, stream>>>(boxesS, nval, out + OFF2);
}

// Round 2
// 1995.973 us; speedup vs baseline: 2.0960x; 2.0960x over previous
//
#include <hip/hip_runtime.h>
#include <math.h>

#define HH 64
#define WW 64
#define NIMG 4
#define CIN 512
#define AA 9
#define HWA (HH*WW*AA)          // 36864
#define PRE_NMS 6000
#define POST_NMS 300
#define NEGV (-1e10f)
#define NEGK 0xD01502F9u        // descending-order key of -1e10f
#define NWORD 94                // ceil(6000/64)

#define OFF1 589824             // rpn_scores
#define OFF2 884736             // rois
#define OFF3 889536             // roi_indices
#define OFF4 890736             // anchors

typedef unsigned int u32;
typedef unsigned long long u64;

// ---------------- W transpose: W[co][ci][tap] -> Wt[ci*9+tap][co] ----------------
__global__ __launch_bounds__(256) void k_transpose(const float* __restrict__ Wsrc,
                                                   float* __restrict__ Wt)
{
    __shared__ float tile[64][65];
    int rt0 = blockIdx.x * 64;   // ci*9+tap tile (4608/64 = 72)
    int co0 = blockIdx.y * 64;   // co tile (512/64 = 8)
    int t = threadIdx.x;
    #pragma unroll
    for (int l = 0; l < 16; ++l) {
        int i = l * 256 + t;
        int rr = i & 63, cc = i >> 6;
        tile[cc][rr] = Wsrc[(size_t)(co0 + cc) * 4608 + rt0 + rr];
    }
    __syncthreads();
    #pragma unroll
    for (int l = 0; l < 16; ++l) {
        int i = l * 256 + t;
        int cc = i & 63, rr = i >> 6;
        Wt[(size_t)(rt0 + rr) * 512 + co0 + cc] = tile[cc][rr];
    }
}

// ---------------- conv 3x3 (pad 1) + bias + ReLU ----------------
// Block: 256 threads, tile = 64 cout x (2 rows x 64 cols). Grid (8, 32, 4).
__global__ __launch_bounds__(256, 2) void k_conv3x3(const float* __restrict__ x,
                                                    const float* __restrict__ wt,
                                                    const float* __restrict__ bias,
                                                    float* __restrict__ mid)
{
    __shared__ float sW[72 * 64];     // [ci*9+tap][co]
    __shared__ float sI[8][4][68];    // [ci][row y0-1..y0+2][col -1..66]
    const int t = threadIdx.x;
    const int n = blockIdx.z, co0 = blockIdx.x * 64, y0 = blockIdx.y * 2;
    const int tx = t & 15, ty = t >> 4;
    const int x0 = tx * 4;

    float acc[4][2][4];
    #pragma unroll
    for (int c = 0; c < 4; ++c)
        #pragma unroll
        for (int r = 0; r < 2; ++r)
            #pragma unroll
            for (int j = 0; j < 4; ++j) acc[c][r][j] = 0.f;

    for (int ci0 = 0; ci0 < 512; ci0 += 8) {
        __syncthreads();
        // stage weights: 4608 floats, coalesced from transposed layout
        #pragma unroll
        for (int l = 0; l < 18; ++l) {
            int i = l * 256 + t;
            int tc = i >> 6, co = i & 63;
            sW[i] = wt[(size_t)(ci0 * 9 + tc) * 512 + co0 + co];
        }
        // stage input rows y0-1..y0+2 for 8 channels
        #pragma unroll
        for (int l = 0; l < 8; ++l) {
            int i = l * 256 + t;
            int col = i & 63, r = (i >> 6) & 3, ci = i >> 8;
            int gy = y0 + r - 1;
            float v = 0.f;
            if (gy >= 0 && gy < HH)
                v = x[((size_t)(n * CIN + ci0 + ci) * HH + gy) * WW + col];
            sI[ci][r][col + 1] = v;
        }
        if (t < 32) {
            int ci = t >> 2, r = t & 3;
            sI[ci][r][0] = 0.f; sI[ci][r][65] = 0.f; sI[ci][r][66] = 0.f; sI[ci][r][67] = 0.f;
        }
        __syncthreads();

        #pragma unroll
        for (int ci = 0; ci < 8; ++ci) {
            float row[4][6];
            #pragma unroll
            for (int r = 0; r < 4; ++r)
                #pragma unroll
                for (int j = 0; j < 6; ++j) row[r][j] = sI[ci][r][x0 + j];
            #pragma unroll
            for (int ky = 0; ky < 3; ++ky) {
                float wv[3][4];
                #pragma unroll
                for (int kx = 0; kx < 3; ++kx)
                    #pragma unroll
                    for (int c = 0; c < 4; ++c)
                        wv[kx][c] = sW[(ci * 9 + ky * 3 + kx) * 64 + ty * 4 + c];
                #pragma unroll
                for (int kx = 0; kx < 3; ++kx)
                    #pragma unroll
                    for (int c = 0; c < 4; ++c)
                        #pragma unroll
                        for (int j = 0; j < 4; ++j) {
                            acc[c][0][j] += wv[kx][c] * row[ky][kx + j];
                            acc[c][1][j] += wv[kx][c] * row[ky + 1][kx + j];
                        }
            }
        }
    }
    // epilogue: bias + relu
    #pragma unroll
    for (int c = 0; c < 4; ++c) {
        float bv = bias[co0 + ty * 4 + c];
        #pragma unroll
        for (int r = 0; r < 2; ++r) {
            #pragma unroll
            for (int j = 0; j < 4; ++j) {
                float v = acc[c][r][j] + bv;
                mid[((size_t)(n * 512 + co0 + ty * 4 + c) * HH + y0 + r) * WW + x0 + j] =
                    v > 0.f ? v : 0.f;
            }
        }
    }
}

// ---------------- 1x1 heads + box decode + score keys ----------------
__global__ __launch_bounds__(256) void k_heads(const float* __restrict__ mid,
                                               const float* __restrict__ Wsc,
                                               const float* __restrict__ bsc,
                                               const float* __restrict__ Wlc,
                                               const float* __restrict__ blc,
                                               const int* __restrict__ ph,
                                               const int* __restrict__ pw,
                                               float* __restrict__ out,
                                               float* __restrict__ boxes,
                                               u32* __restrict__ key)
{
    int p = blockIdx.x * 256 + threadIdx.x;   // 0..16383
    int n = p >> 12, pi = p & 4095;
    int y = pi >> 6, xq = pi & 63;

    float accS[18], accL[36];
    #pragma unroll
    for (int c = 0; c < 18; ++c) accS[c] = bsc[c];
    #pragma unroll
    for (int c = 0; c < 36; ++c) accL[c] = blc[c];

    const float* mbase = mid + (size_t)n * (512 * 4096) + pi;
    #pragma unroll 8
    for (int ci = 0; ci < 512; ++ci) {
        float m = mbase[(size_t)ci * 4096];
        #pragma unroll
        for (int c = 0; c < 18; ++c) accS[c] += Wsc[c * 512 + ci] * m;
        #pragma unroll
        for (int c = 0; c < 36; ++c) accL[c] += Wlc[c * 512 + ci] * m;
    }

    float* o0 = out + (size_t)n * 147456;
    float* o1 = out + OFF1 + (size_t)n * 73728;
    float IHf = (float)(*ph), IWf = (float)(*pw);

    #pragma unroll
    for (int a = 0; a < 9; ++a) {
        #pragma unroll
        for (int j = 0; j < 2; ++j) o1[(pi * 9 + a) * 2 + j] = accS[a * 2 + j];
        #pragma unroll
        for (int j = 0; j < 4; ++j) o0[(pi * 9 + a) * 4 + j] = accL[a * 4 + j];

        // softmax fg (max-subtracted like jax.nn.softmax)
        float s0 = accS[a * 2], s1 = accS[a * 2 + 1];
        float mm = fmaxf(s0, s1);
        float e0 = expf(s0 - mm), e1 = expf(s1 - mm);
        float fg = e1 / (e0 + e1);

        // anchor (base in f64 like numpy, then f32 add of exact shift)
        int ri = a / 3, si = a - ri * 3;
        double s = (double)(8 << si);
        double rr = (ri == 0) ? 0.5 : ((ri == 1) ? 1.0 : 2.0);
        double hh = 16.0 * s * sqrt(rr);
        double wd = 16.0 * s * sqrt(1.0 / rr);
        float a0 = (float)(8.0 - hh * 0.5) + (float)(y * 16);
        float a1 = (float)(8.0 - wd * 0.5) + (float)(xq * 16);
        float a2 = (float)(8.0 + hh * 0.5) + (float)(y * 16);
        float a3 = (float)(8.0 + wd * 0.5) + (float)(xq * 16);

        // loc2bbox
        float h = a2 - a0, w = a3 - a1;
        float cy = a0 + 0.5f * h, cx = a1 + 0.5f * w;
        float dy = accL[a * 4 + 0], dx = accL[a * 4 + 1];
        float dh = accL[a * 4 + 2], dw = accL[a * 4 + 3];
        float ncy = dy * h + cy, ncx = dx * w + cx;
        float nh = expf(dh) * h, nw = expf(dw) * w;
        float b0 = fminf(fmaxf(ncy - 0.5f * nh, 0.f), IHf);
        float b1 = fminf(fmaxf(ncx - 0.5f * nw, 0.f), IWf);
        float b2 = fminf(fmaxf(ncy + 0.5f * nh, 0.f), IHf);
        float b3 = fminf(fmaxf(ncx + 0.5f * nw, 0.f), IWf);

        bool ok = (b2 - b0 >= 16.0f) && (b3 - b1 >= 16.0f);
        float sc = ok ? fg : NEGV;

        int gi = n * HWA + pi * 9 + a;
        float4 bx = make_float4(b0, b1, b2, b3);
        ((float4*)boxes)[gi] = bx;
        u32 u = __float_as_uint(sc);
        u32 kasc = (u & 0x80000000u) ? ~u : (u | 0x80000000u);
        key[gi] = ~kasc;   // ascending key == descending score
    }
}

// ---------------- anchors out + roi_indices + zero rois ----------------
__global__ void k_misc(float* __restrict__ out)
{
    int i = blockIdx.x * 256 + threadIdx.x;
    if (i < 4800) out[OFF2 + i] = 0.f;
    if (i < 1200) out[OFF3 + i] = (float)(i / 300);
    if (i < HWA) {
        int pi = i / 9, a = i - pi * 9;
        int y = pi >> 6, xq = pi & 63;
        int ri = a / 3, si = a - ri * 3;
        double s = (double)(8 << si);
        double rr = (ri == 0) ? 0.5 : ((ri == 1) ? 1.0 : 2.0);
        double hh = 16.0 * s * sqrt(rr);
        double wd = 16.0 * s * sqrt(1.0 / rr);
        out[OFF4 + i * 4 + 0] = (float)(8.0 - hh * 0.5) + (float)(y * 16);
        out[OFF4 + i * 4 + 1] = (float)(8.0 - wd * 0.5) + (float)(xq * 16);
        out[OFF4 + i * 4 + 2] = (float)(8.0 + hh * 0.5) + (float)(y * 16);
        out[OFF4 + i * 4 + 3] = (float)(8.0 + wd * 0.5) + (float)(xq * 16);
    }
}

// ---------------- exact rank-6000 radix select + compact ----------------
__global__ __launch_bounds__(1024) void k_select(const u32* __restrict__ key,
                                                 u64* __restrict__ cmp,
                                                 int* __restrict__ nvalid)
{
    __shared__ int hist[256];
    __shared__ u32 sPref;
    __shared__ int sR;
    __shared__ int cLess, cEq, cVal;
    int n = blockIdx.x, t = threadIdx.x;
    const u32* k0 = key + (size_t)n * HWA;

    u32 pref = 0, mask = 0;
    int R = PRE_NMS;
    for (int pass = 0; pass < 4; ++pass) {
        int shift = 24 - pass * 8;
        if (t < 256) hist[t] = 0;
        __syncthreads();
        for (int i = t; i < HWA; i += 1024) {
            u32 k = k0[i];
            if ((k & mask) == pref) atomicAdd(&hist[(k >> shift) & 255], 1);
        }
        __syncthreads();
        if (t == 0) {
            int cum = 0;
            for (int b = 0; b < 256; ++b) {
                int c = hist[b];
                if (cum + c >= R) { sPref = pref | ((u32)b << shift); sR = R - cum; break; }
                cum += c;
            }
        }
        __syncthreads();
        pref = sPref; R = sR; mask |= (0xFFu << shift);
        __syncthreads();
    }
    u32 T = pref;   // exact 6000th smallest key
    if (t == 0) { cLess = 0; cEq = 0; cVal = 0; }
    __syncthreads();
    for (int i = t; i < HWA; i += 1024) {
        u32 k = k0[i];
        if (k < NEGK) atomicAdd(&cVal, 1);
        if (k < T) {
            int p = atomicAdd(&cLess, 1);
            cmp[(size_t)n * 8192 + p] = ((u64)k << 32) | (u32)i;
        } else if (k == T) {
            int p = atomicAdd(&cEq, 1);
            if (p < R) cmp[(size_t)n * 8192 + (PRE_NMS - 1 - p)] = ((u64)k << 32) | (u32)i;
        }
    }
    for (int i = PRE_NMS + t; i < 8192; i += 1024) cmp[(size_t)n * 8192 + i] = ~0ull;
    __syncthreads();
    if (t == 0) nvalid[n] = cVal < PRE_NMS ? cVal : PRE_NMS;
}

// ---------------- bitonic sort of 8192 (key<<32|idx) in LDS ----------------
__global__ __launch_bounds__(1024) void k_sort(const u64* __restrict__ cmp,
                                               const float* __restrict__ boxes,
                                               float* __restrict__ boxesS)
{
    __shared__ u64 sK[8192];   // exactly 64 KiB
    int n = blockIdx.x, t = threadIdx.x;
    for (int i = t; i < 8192; i += 1024) sK[i] = cmp[(size_t)n * 8192 + i];
    for (unsigned k = 2; k <= 8192; k <<= 1) {
        for (unsigned j = k >> 1; j > 0; j >>= 1) {
            __syncthreads();
            #pragma unroll
            for (int v = 0; v < 8; ++v) {
                int i = v * 1024 + t;
                int ixj = i ^ (int)j;
                if (ixj > i) {
                    u64 a = sK[i], b = sK[ixj];
                    bool up = ((i & (int)k) == 0);
                    if (up ? (a > b) : (a < b)) { sK[i] = b; sK[ixj] = a; }
                }
            }
        }
    }
    __syncthreads();
    const float4* bsrc = (const float4*)boxes + (size_t)n * HWA;
    float4* bdst = (float4*)boxesS + (size_t)n * PRE_NMS;
    for (int i = t; i < PRE_NMS; i += 1024) {
        u32 idx = (u32)(sK[i] & 0xFFFFFFFFu);
        bdst[i] = bsrc[idx];
    }
}

// ---------------- IoU suppression bitmask: mask[n][i][w] ----------------
// bit b of word w set  <=>  iou(box i, box w*64+b) > 0.7
__global__ __launch_bounds__(64) void k_iou(const float* __restrict__ boxesS,
                                            u64* __restrict__ mask)
{
    __shared__ float4 cb[64];
    int w = blockIdx.x, ic = blockIdx.y, n = blockIdx.z;
    int t = threadIdx.x;
    const float4* B = (const float4*)boxesS + (size_t)n * PRE_NMS;
    int jc = w * 64 + t;
    cb[t] = (jc < PRE_NMS) ? B[jc] : make_float4(0.f, 0.f, 0.f, 0.f);
    __syncthreads();
    int i = ic * 64 + t;
    if (i >= PRE_NMS) return;
    float4 bb = B[i];
    float area1 = (bb.z - bb.x) * (bb.w - bb.y);
    u64 m = 0;
    #pragma unroll 8
    for (int j = 0; j < 64; ++j) {
        float4 o = cb[j];
        float ty_ = fmaxf(bb.x, o.x), tx_ = fmaxf(bb.y, o.y);
        float by_ = fminf(bb.z, o.z), bx_ = fminf(bb.w, o.w);
        float inter = fmaxf(by_ - ty_, 0.f) * fmaxf(bx_ - tx_, 0.f);
        float area2 = (o.z - o.x) * (o.w - o.y);
        float iou = inter / (area1 + area2 - inter + 1e-9f);
        if (iou > 0.7f) m |= (1ull << j);
    }
    mask[((size_t)n * PRE_NMS + i) * NWORD + w] = m;
}

// ---------------- greedy bitmask NMS scan (1 block / image) ----------------
__global__ __launch_bounds__(128) void k_nms2(const u64* __restrict__ mask,
                                              const int* __restrict__ nvalid,
                                              const float* __restrict__ boxesS,
                                              float* __restrict__ rois)
{
    __shared__ u64 rem[NWORD];
    __shared__ int sSel;
    int n = blockIdx.x, t = threadIdx.x;
    int nv = nvalid[n];
    if (t < NWORD) rem[t] = 0;
    __syncthreads();
    const u64* M = mask + (size_t)n * PRE_NMS * NWORD;
    const float4* B = (const float4*)boxesS + (size_t)n * PRE_NMS;
    int cnt = 0;
    int i = 0;   // live only on t==0
    while (cnt < POST_NMS) {
        if (t == 0) {
            int sel = -1;
            while (i < nv) {
                int w = i >> 6, b = i & 63;
                u64 avail = (~rem[w]) >> b;
                if (avail) {
                    int cand = i + __builtin_ctzll(avail);
                    if (cand < nv) sel = cand;
                    break;
                }
                i = (w + 1) << 6;
            }
            sSel = sel;
        }
        __syncthreads();
        int sel = sSel;
        if (sel < 0) break;
        if (t == 0) {
            float4 bb = B[sel];
            float* orow = rois + (size_t)(n * POST_NMS + cnt) * 4;
            orow[0] = bb.x; orow[1] = bb.y; orow[2] = bb.z; orow[3] = bb.w;
            i = sel + 1;
        }
        if (t < NWORD) rem[t] |= M[(size_t)sel * NWORD + t];
        cnt++;
        __syncthreads();
    }
}

extern "C" void kernel_launch(void* const* d_in, const int* in_sizes, int n_in,
                              void* d_out, int out_size, void* d_ws, size_t ws_size,
                              hipStream_t stream)
{
    const float* x  = (const float*)d_in[0];
    const float* W1 = (const float*)d_in[1];
    const float* b1 = (const float*)d_in[2];
    const float* Ws = (const float*)d_in[3];
    const float* bs = (const float*)d_in[4];
    const float* Wl = (const float*)d_in[5];
    const float* bl = (const float*)d_in[6];
    const int* ih   = (const int*)d_in[7];
    const int* iw   = (const int*)d_in[8];
    float* out = (float*)d_out;
    char* ws = (char*)d_ws;

    float* Wt     = (float*)(ws);                 //  9,437,184 B
    float* mid    = (float*)(ws + 9437184);       // 33,554,432 B
    float* boxes  = (float*)(ws + 42991616);      //  2,359,296 B
    u32*   key    = (u32*)  (ws + 45350912);      //    589,824 B
    u64*   cmp    = (u64*)  (ws + 45940736);      //    262,144 B
    float* boxesS = (float*)(ws + 46202880);      //    384,000 B
    int*   nval   = (int*)  (ws + 46586880);      //         16 B
    // mask reuses mid's region (mid is dead after k_heads): 4*6000*94*8 = 18,048,000 B
    u64*   iomask = (u64*)  (ws + 9437184);

    k_transpose<<<dim3(72, 8), 256, 0, stream>>>(W1, Wt);
    k_conv3x3<<<dim3(8, 32, 4), 256, 0, stream>>>(x, Wt, b1, mid);
    k_heads<<<64, 256, 0, stream>>>(mid, Ws, bs, Wl, bl, ih, iw, out, boxes, key);
    k_misc<<<144, 256, 0, stream>>>(out);
    k_select<<<4, 1024, 0, stream>>>(key, cmp, nval);
    k_sort<<<4, 1024, 0, stream>>>(cmp, boxes, boxesS);
    k_iou<<<dim3(NWORD, NWORD, NIMG), 64, 0, stream>>>(boxesS, iomask);
    k_nms2<<<NIMG, 128, 0, stream>>>(iomask, nval, boxesS, out + OFF2);
}

// Round 3
// 1570.385 us; speedup vs baseline: 2.6640x; 1.2710x over previous
//
#include <hip/hip_runtime.h>
#include <math.h>

#define HH 64
#define WW 64
#define NIMG 4
#define CIN 512
#define AA 9
#define HWA (HH*WW*AA)          // 36864
#define PRE_NMS 6000
#define POST_NMS 300
#define NEGV (-1e10f)
#define NEGK 0xD01502F9u        // descending-order key of -1e10f
#define NWORD 94                // ceil(6000/64)

#define OFF1 589824             // rpn_scores
#define OFF2 884736             // rois
#define OFF3 889536             // roi_indices
#define OFF4 890736             // anchors

typedef unsigned int u32;
typedef unsigned long long u64;

// ---------------- W transpose: W[co][ci][tap] -> Wt[ci*9+tap][co] ----------------
__global__ __launch_bounds__(256) void k_transpose(const float* __restrict__ Wsrc,
                                                   float* __restrict__ Wt)
{
    __shared__ float tile[64][65];
    int rt0 = blockIdx.x * 64;   // ci*9+tap tile (4608/64 = 72)
    int co0 = blockIdx.y * 64;   // co tile (512/64 = 8)
    int t = threadIdx.x;
    #pragma unroll
    for (int l = 0; l < 16; ++l) {
        int i = l * 256 + t;
        int rr = i & 63, cc = i >> 6;
        tile[cc][rr] = Wsrc[(size_t)(co0 + cc) * 4608 + rt0 + rr];
    }
    __syncthreads();
    #pragma unroll
    for (int l = 0; l < 16; ++l) {
        int i = l * 256 + t;
        int cc = i & 63, rr = i >> 6;
        Wt[(size_t)(rt0 + rr) * 512 + co0 + cc] = tile[cc][rr];
    }
}

// ---------------- conv 3x3 (pad 1) + bias + ReLU ----------------
// Block: 256 threads, tile = 64 cout x (2 rows x 64 cols). Grid (8, 32, 4).
__global__ __launch_bounds__(256, 2) void k_conv3x3(const float* __restrict__ x,
                                                    const float* __restrict__ wt,
                                                    const float* __restrict__ bias,
                                                    float* __restrict__ mid)
{
    __shared__ float sW[72 * 64];     // [ci*9+tap][co]
    __shared__ float sI[8][4][72];    // [ci][row y0-1..y0+2][col -1..66] (+pad to 72)
    const int t = threadIdx.x;
    const int n = blockIdx.z, co0 = blockIdx.x * 64, y0 = blockIdx.y * 2;
    const int tx = t & 15, ty = t >> 4;
    const int x0 = tx * 4;

    float acc[4][2][4];
    #pragma unroll
    for (int c = 0; c < 4; ++c)
        #pragma unroll
        for (int r = 0; r < 2; ++r)
            #pragma unroll
            for (int j = 0; j < 4; ++j) acc[c][r][j] = 0.f;

    for (int ci0 = 0; ci0 < 512; ci0 += 8) {
        __syncthreads();
        // stage weights: 4608 floats, coalesced from transposed layout
        #pragma unroll
        for (int l = 0; l < 18; ++l) {
            int i = l * 256 + t;
            int tc = i >> 6, co = i & 63;
            sW[i] = wt[(size_t)(ci0 * 9 + tc) * 512 + co0 + co];
        }
        // stage input rows y0-1..y0+2 for 8 channels
        #pragma unroll
        for (int l = 0; l < 8; ++l) {
            int i = l * 256 + t;
            int col = i & 63, r = (i >> 6) & 3, ci = i >> 8;
            int gy = y0 + r - 1;
            float v = 0.f;
            if (gy >= 0 && gy < HH)
                v = x[((size_t)(n * CIN + ci0 + ci) * HH + gy) * WW + col];
            sI[ci][r][col + 1] = v;
        }
        if (t < 32) {
            int ci = t >> 2, r = t & 3;
            sI[ci][r][0] = 0.f; sI[ci][r][65] = 0.f; sI[ci][r][66] = 0.f; sI[ci][r][67] = 0.f;
        }
        __syncthreads();

        #pragma unroll
        for (int ci = 0; ci < 8; ++ci) {
            float row[4][6];
            #pragma unroll
            for (int r = 0; r < 4; ++r)
                #pragma unroll
                for (int j = 0; j < 6; ++j) row[r][j] = sI[ci][r][x0 + j];
            #pragma unroll
            for (int ky = 0; ky < 3; ++ky) {
                float wv[3][4];
                #pragma unroll
                for (int kx = 0; kx < 3; ++kx)
                    #pragma unroll
                    for (int c = 0; c < 4; ++c)
                        wv[kx][c] = sW[(ci * 9 + ky * 3 + kx) * 64 + ty * 4 + c];
                #pragma unroll
                for (int kx = 0; kx < 3; ++kx)
                    #pragma unroll
                    for (int c = 0; c < 4; ++c)
                        #pragma unroll
                        for (int j = 0; j < 4; ++j) {
                            acc[c][0][j] += wv[kx][c] * row[ky][kx + j];
                            acc[c][1][j] += wv[kx][c] * row[ky + 1][kx + j];
                        }
            }
        }
    }
    // epilogue: bias + relu
    #pragma unroll
    for (int c = 0; c < 4; ++c) {
        float bv = bias[co0 + ty * 4 + c];
        #pragma unroll
        for (int r = 0; r < 2; ++r) {
            #pragma unroll
            for (int j = 0; j < 4; ++j) {
                float v = acc[c][r][j] + bv;
                mid[((size_t)(n * 512 + co0 + ty * 4 + c) * HH + y0 + r) * WW + x0 + j] =
                    v > 0.f ? v : 0.f;
            }
        }
    }
}

// ---------------- head weights -> [ci][co] (co: 0..17 score, 18..53 loc, pad 64) ----
__global__ __launch_bounds__(256) void k_htrans(const float* __restrict__ Ws,
                                                const float* __restrict__ Wl,
                                                float* __restrict__ Wt2)
{
    int i = blockIdx.x * 256 + threadIdx.x;   // 512*64
    if (i >= 512 * 64) return;
    int ci = i >> 6, co = i & 63;
    float v = 0.f;
    if (co < 18) v = Ws[co * 512 + ci];
    else if (co < 54) v = Wl[(co - 18) * 512 + ci];
    Wt2[i] = v;
}

// ---------------- 1x1 heads as GEMM: sraw[n][co64][px4096] ----------------
// Block 256: tile 64px x 64co, thread = 4co x 4px. Grid (64 px-tiles, 4 n).
__global__ __launch_bounds__(256) void k_hgemm(const float* __restrict__ mid,
                                               const float* __restrict__ Wt2,
                                               float* __restrict__ sraw)
{
    __shared__ float sM[32][64];   // [ci][px]
    __shared__ float sW2[32][64];  // [ci][co]
    const int t = threadIdx.x;
    const int px0 = blockIdx.x * 64, n = blockIdx.y;
    const int tx = t & 15, ty = t >> 4;

    float acc[4][4];
    #pragma unroll
    for (int c = 0; c < 4; ++c)
        #pragma unroll
        for (int j = 0; j < 4; ++j) acc[c][j] = 0.f;

    for (int ci0 = 0; ci0 < 512; ci0 += 32) {
        __syncthreads();
        #pragma unroll
        for (int l = 0; l < 8; ++l) {
            int i = l * 256 + t;
            int ci = i >> 6, px = i & 63;
            sM[ci][px] = mid[((size_t)n * 512 + ci0 + ci) * 4096 + px0 + px];
            sW2[ci][px] = Wt2[(size_t)(ci0 + ci) * 64 + px];
        }
        __syncthreads();
        #pragma unroll
        for (int ci = 0; ci < 32; ++ci) {
            float mv[4], wv[4];
            #pragma unroll
            for (int j = 0; j < 4; ++j) mv[j] = sM[ci][tx * 4 + j];
            #pragma unroll
            for (int c = 0; c < 4; ++c) wv[c] = sW2[ci][ty * 4 + c];
            #pragma unroll
            for (int c = 0; c < 4; ++c)
                #pragma unroll
                for (int j = 0; j < 4; ++j) acc[c][j] += wv[c] * mv[j];
        }
    }
    #pragma unroll
    for (int c = 0; c < 4; ++c) {
        float4 v = make_float4(acc[c][0], acc[c][1], acc[c][2], acc[c][3]);
        *(float4*)&sraw[((size_t)n * 64 + ty * 4 + c) * 4096 + px0 + tx * 4] = v;
    }
}

// ---------------- decode: softmax, loc2bbox, clip, keys, head outputs ----------------
__global__ __launch_bounds__(256) void k_decode(const float* __restrict__ sraw,
                                                const float* __restrict__ bsc,
                                                const float* __restrict__ blc,
                                                const int* __restrict__ ph,
                                                const int* __restrict__ pw,
                                                float* __restrict__ out,
                                                float* __restrict__ boxes,
                                                u32* __restrict__ key)
{
    int p = blockIdx.x * 256 + threadIdx.x;   // 0..16383
    int n = p >> 12, pi = p & 4095;
    int y = pi >> 6, xq = pi & 63;

    const float* S = sraw + (size_t)n * 64 * 4096 + pi;
    float* o0 = out + (size_t)n * 147456;
    float* o1 = out + OFF1 + (size_t)n * 73728;
    float IHf = (float)(*ph), IWf = (float)(*pw);

    #pragma unroll
    for (int a = 0; a < 9; ++a) {
        float s0 = S[(size_t)(2 * a) * 4096] + bsc[2 * a];
        float s1 = S[(size_t)(2 * a + 1) * 4096] + bsc[2 * a + 1];
        float dy = S[(size_t)(18 + 4 * a) * 4096] + blc[4 * a];
        float dx = S[(size_t)(19 + 4 * a) * 4096] + blc[4 * a + 1];
        float dh = S[(size_t)(20 + 4 * a) * 4096] + blc[4 * a + 2];
        float dw = S[(size_t)(21 + 4 * a) * 4096] + blc[4 * a + 3];

        o1[(pi * 9 + a) * 2 + 0] = s0;
        o1[(pi * 9 + a) * 2 + 1] = s1;
        o0[(pi * 9 + a) * 4 + 0] = dy;
        o0[(pi * 9 + a) * 4 + 1] = dx;
        o0[(pi * 9 + a) * 4 + 2] = dh;
        o0[(pi * 9 + a) * 4 + 3] = dw;

        // softmax fg (max-subtracted like jax.nn.softmax)
        float mm = fmaxf(s0, s1);
        float e0 = expf(s0 - mm), e1 = expf(s1 - mm);
        float fg = e1 / (e0 + e1);

        // anchor (base in f64 like numpy, then f32 add of exact shift)
        int ri = a / 3, si = a - ri * 3;
        double s = (double)(8 << si);
        double rr = (ri == 0) ? 0.5 : ((ri == 1) ? 1.0 : 2.0);
        double hh = 16.0 * s * sqrt(rr);
        double wd = 16.0 * s * sqrt(1.0 / rr);
        float a0 = (float)(8.0 - hh * 0.5) + (float)(y * 16);
        float a1 = (float)(8.0 - wd * 0.5) + (float)(xq * 16);
        float a2 = (float)(8.0 + hh * 0.5) + (float)(y * 16);
        float a3 = (float)(8.0 + wd * 0.5) + (float)(xq * 16);

        // loc2bbox
        float h = a2 - a0, w = a3 - a1;
        float cy = a0 + 0.5f * h, cx = a1 + 0.5f * w;
        float ncy = dy * h + cy, ncx = dx * w + cx;
        float nh = expf(dh) * h, nw = expf(dw) * w;
        float b0 = fminf(fmaxf(ncy - 0.5f * nh, 0.f), IHf);
        float b1 = fminf(fmaxf(ncx - 0.5f * nw, 0.f), IWf);
        float b2 = fminf(fmaxf(ncy + 0.5f * nh, 0.f), IHf);
        float b3 = fminf(fmaxf(ncx + 0.5f * nw, 0.f), IWf);

        bool ok = (b2 - b0 >= 16.0f) && (b3 - b1 >= 16.0f);
        float sc = ok ? fg : NEGV;

        int gi = n * HWA + pi * 9 + a;
        ((float4*)boxes)[gi] = make_float4(b0, b1, b2, b3);
        u32 u = __float_as_uint(sc);
        u32 kasc = (u & 0x80000000u) ? ~u : (u | 0x80000000u);
        key[gi] = ~kasc;   // ascending key == descending score
    }
}

// ---------------- anchors out + roi_indices + zero rois ----------------
__global__ void k_misc(float* __restrict__ out)
{
    int i = blockIdx.x * 256 + threadIdx.x;
    if (i < 4800) out[OFF2 + i] = 0.f;
    if (i < 1200) out[OFF3 + i] = (float)(i / 300);
    if (i < HWA) {
        int pi = i / 9, a = i - pi * 9;
        int y = pi >> 6, xq = pi & 63;
        int ri = a / 3, si = a - ri * 3;
        double s = (double)(8 << si);
        double rr = (ri == 0) ? 0.5 : ((ri == 1) ? 1.0 : 2.0);
        double hh = 16.0 * s * sqrt(rr);
        double wd = 16.0 * s * sqrt(1.0 / rr);
        out[OFF4 + i * 4 + 0] = (float)(8.0 - hh * 0.5) + (float)(y * 16);
        out[OFF4 + i * 4 + 1] = (float)(8.0 - wd * 0.5) + (float)(xq * 16);
        out[OFF4 + i * 4 + 2] = (float)(8.0 + hh * 0.5) + (float)(y * 16);
        out[OFF4 + i * 4 + 3] = (float)(8.0 + wd * 0.5) + (float)(xq * 16);
    }
}

// ---------------- exact rank-6000 radix select + compact ----------------
__global__ __launch_bounds__(1024) void k_select(const u32* __restrict__ key,
                                                 u64* __restrict__ cmp,
                                                 int* __restrict__ nvalid)
{
    __shared__ int hist[256];
    __shared__ u32 sPref;
    __shared__ int sR;
    __shared__ int cLess, cEq, cVal;
    int n = blockIdx.x, t = threadIdx.x;
    const u32* k0 = key + (size_t)n * HWA;

    u32 pref = 0, mask = 0;
    int R = PRE_NMS;
    for (int pass = 0; pass < 4; ++pass) {
        int shift = 24 - pass * 8;
        if (t < 256) hist[t] = 0;
        __syncthreads();
        for (int i = t; i < HWA; i += 1024) {
            u32 k = k0[i];
            if ((k & mask) == pref) atomicAdd(&hist[(k >> shift) & 255], 1);
        }
        __syncthreads();
        if (t == 0) {
            int cum = 0;
            for (int b = 0; b < 256; ++b) {
                int c = hist[b];
                if (cum + c >= R) { sPref = pref | ((u32)b << shift); sR = R - cum; break; }
                cum += c;
            }
        }
        __syncthreads();
        pref = sPref; R = sR; mask |= (0xFFu << shift);
        __syncthreads();
    }
    u32 T = pref;   // exact 6000th smallest key
    if (t == 0) { cLess = 0; cEq = 0; cVal = 0; }
    __syncthreads();
    for (int i = t; i < HWA; i += 1024) {
        u32 k = k0[i];
        if (k < NEGK) atomicAdd(&cVal, 1);
        if (k < T) {
            int p = atomicAdd(&cLess, 1);
            cmp[(size_t)n * 8192 + p] = ((u64)k << 32) | (u32)i;
        } else if (k == T) {
            int p = atomicAdd(&cEq, 1);
            if (p < R) cmp[(size_t)n * 8192 + (PRE_NMS - 1 - p)] = ((u64)k << 32) | (u32)i;
        }
    }
    for (int i = PRE_NMS + t; i < 8192; i += 1024) cmp[(size_t)n * 8192 + i] = ~0ull;
    __syncthreads();
    if (t == 0) nvalid[n] = cVal < PRE_NMS ? cVal : PRE_NMS;
}

// ---------------- bitonic sort of 8192 (key<<32|idx) in LDS ----------------
__global__ __launch_bounds__(1024) void k_sort(const u64* __restrict__ cmp,
                                               const float* __restrict__ boxes,
                                               float* __restrict__ boxesS)
{
    __shared__ u64 sK[8192];   // exactly 64 KiB
    int n = blockIdx.x, t = threadIdx.x;
    for (int i = t; i < 8192; i += 1024) sK[i] = cmp[(size_t)n * 8192 + i];
    for (unsigned k = 2; k <= 8192; k <<= 1) {
        for (unsigned j = k >> 1; j > 0; j >>= 1) {
            __syncthreads();
            #pragma unroll
            for (int v = 0; v < 8; ++v) {
                int i = v * 1024 + t;
                int ixj = i ^ (int)j;
                if (ixj > i) {
                    u64 a = sK[i], b = sK[ixj];
                    bool up = ((i & (int)k) == 0);
                    if (up ? (a > b) : (a < b)) { sK[i] = b; sK[ixj] = a; }
                }
            }
        }
    }
    __syncthreads();
    const float4* bsrc = (const float4*)boxes + (size_t)n * HWA;
    float4* bdst = (float4*)boxesS + (size_t)n * PRE_NMS;
    for (int i = t; i < PRE_NMS; i += 1024) {
        u32 idx = (u32)(sK[i] & 0xFFFFFFFFu);
        bdst[i] = bsrc[idx];
    }
}

// ---------------- IoU suppression bitmask: mask[n][i][w] ----------------
__global__ __launch_bounds__(64) void k_iou(const float* __restrict__ boxesS,
                                            u64* __restrict__ mask)
{
    __shared__ float4 cb[64];
    int w = blockIdx.x, ic = blockIdx.y, n = blockIdx.z;
    int t = threadIdx.x;
    const float4* B = (const float4*)boxesS + (size_t)n * PRE_NMS;
    int jc = w * 64 + t;
    cb[t] = (jc < PRE_NMS) ? B[jc] : make_float4(0.f, 0.f, 0.f, 0.f);
    __syncthreads();
    int i = ic * 64 + t;
    if (i >= PRE_NMS) return;
    float4 bb = B[i];
    float area1 = (bb.z - bb.x) * (bb.w - bb.y);
    u64 m = 0;
    #pragma unroll 8
    for (int j = 0; j < 64; ++j) {
        float4 o = cb[j];
        float ty_ = fmaxf(bb.x, o.x), tx_ = fmaxf(bb.y, o.y);
        float by_ = fminf(bb.z, o.z), bx_ = fminf(bb.w, o.w);
        float inter = fmaxf(by_ - ty_, 0.f) * fmaxf(bx_ - tx_, 0.f);
        float area2 = (o.z - o.x) * (o.w - o.y);
        float iou = inter / (area1 + area2 - inter + 1e-9f);
        if (iou > 0.7f) m |= (1ull << j);
    }
    mask[((size_t)n * PRE_NMS + i) * NWORD + w] = m;
}

// ---------------- greedy bitmask NMS scan (1 block / image) ----------------
__global__ __launch_bounds__(128) void k_nms2(const u64* __restrict__ mask,
                                              const int* __restrict__ nvalid,
                                              const float* __restrict__ boxesS,
                                              float* __restrict__ rois)
{
    __shared__ u64 rem[NWORD];
    __shared__ int sSel;
    int n = blockIdx.x, t = threadIdx.x;
    int nv = nvalid[n];
    if (t < NWORD) rem[t] = 0;
    __syncthreads();
    const u64* M = mask + (size_t)n * PRE_NMS * NWORD;
    const float4* B = (const float4*)boxesS + (size_t)n * PRE_NMS;
    int cnt = 0;
    int i = 0;   // live only on t==0
    while (cnt < POST_NMS) {
        if (t == 0) {
            int sel = -1;
            while (i < nv) {
                int w = i >> 6, b = i & 63;
                u64 avail = (~rem[w]) >> b;
                if (avail) {
                    int cand = i + __builtin_ctzll(avail);
                    if (cand < nv) sel = cand;
                    break;
                }
                i = (w + 1) << 6;
            }
            sSel = sel;
        }
        __syncthreads();
        int sel = sSel;
        if (sel < 0) break;
        if (t == 0) {
            float4 bb = B[sel];
            float* orow = rois + (size_t)(n * POST_NMS + cnt) * 4;
            orow[0] = bb.x; orow[1] = bb.y; orow[2] = bb.z; orow[3] = bb.w;
            i = sel + 1;
        }
        if (t < NWORD) rem[t] |= M[(size_t)sel * NWORD + t];
        cnt++;
        __syncthreads();
    }
}

extern "C" void kernel_launch(void* const* d_in, const int* in_sizes, int n_in,
                              void* d_out, int out_size, void* d_ws, size_t ws_size,
                              hipStream_t stream)
{
    const float* x  = (const float*)d_in[0];
    const float* W1 = (const float*)d_in[1];
    const float* b1 = (const float*)d_in[2];
    const float* Ws = (const float*)d_in[3];
    const float* bs = (const float*)d_in[4];
    const float* Wl = (const float*)d_in[5];
    const float* bl = (const float*)d_in[6];
    const int* ih   = (const int*)d_in[7];
    const int* iw   = (const int*)d_in[8];
    float* out = (float*)d_out;
    char* ws = (char*)d_ws;

    float* Wt     = (float*)(ws);                 //  9,437,184 B (dead after conv)
    float* mid    = (float*)(ws + 9437184);       // 33,554,432 B (dead after hgemm)
    float* boxes  = (float*)(ws + 42991616);      //  2,359,296 B
    u32*   key    = (u32*)  (ws + 45350912);      //    589,824 B
    u64*   cmp    = (u64*)  (ws + 45940736);      //    262,144 B
    float* boxesS = (float*)(ws + 46202880);      //    384,000 B
    int*   nval   = (int*)  (ws + 46586880);      //         16 B
    // reuse dead Wt region after conv:
    float* Wt2    = (float*)(ws);                 //    131,072 B [ci][co64]
    float* sraw   = (float*)(ws + 262144);        //  4,194,304 B [n][co64][px]
    // reuse dead mid region after hgemm:
    u64*   iomask = (u64*)  (ws + 9437184);       // 18,048,000 B

    k_transpose<<<dim3(72, 8), 256, 0, stream>>>(W1, Wt);
    k_conv3x3<<<dim3(8, 32, 4), 256, 0, stream>>>(x, Wt, b1, mid);
    k_htrans<<<128, 256, 0, stream>>>(Ws, Wl, Wt2);
    k_hgemm<<<dim3(64, 4), 256, 0, stream>>>(mid, Wt2, sraw);
    k_decode<<<64, 256, 0, stream>>>(sraw, bs, bl, ih, iw, out, boxes, key);
    k_misc<<<144, 256, 0, stream>>>(out);
    k_select<<<4, 1024, 0, stream>>>(key, cmp, nval);
    k_sort<<<4, 1024, 0, stream>>>(cmp, boxes, boxesS);
    k_iou<<<dim3(NWORD, NWORD, NIMG), 64, 0, stream>>>(boxesS, iomask);
    k_nms2<<<NIMG, 128, 0, stream>>>(iomask, nval, boxesS, out + OFF2);
}

// Round 4
// 1561.455 us; speedup vs baseline: 2.6792x; 1.0057x over previous
//
#include <hip/hip_runtime.h>
#include <math.h>

#define HH 64
#define WW 64
#define NIMG 4
#define CIN 512
#define AA 9
#define HWA (HH*WW*AA)          // 36864
#define PRE_NMS 6000
#define POST_NMS 300
#define NEGV (-1e10f)
#define NEGK 0xD01502F9u        // descending-order key of -1e10f
#define NWORD 94                // ceil(6000/64)

#define OFF1 589824             // rpn_scores
#define OFF2 884736             // rois
#define OFF3 889536             // roi_indices
#define OFF4 890736             // anchors

typedef unsigned int u32;
typedef unsigned long long u64;

// ---------------- W transpose: W[co][ci][tap] -> Wt[ci*9+tap][co] ----------------
__global__ __launch_bounds__(256) void k_transpose(const float* __restrict__ Wsrc,
                                                   float* __restrict__ Wt)
{
    __shared__ float tile[64][65];
    int rt0 = blockIdx.x * 64;   // ci*9+tap tile (4608/64 = 72)
    int co0 = blockIdx.y * 64;   // co tile (512/64 = 8)
    int t = threadIdx.x;
    #pragma unroll
    for (int l = 0; l < 16; ++l) {
        int i = l * 256 + t;
        int rr = i & 63, cc = i >> 6;
        tile[cc][rr] = Wsrc[(size_t)(co0 + cc) * 4608 + rt0 + rr];
    }
    __syncthreads();
    #pragma unroll
    for (int l = 0; l < 16; ++l) {
        int i = l * 256 + t;
        int cc = i & 63, rr = i >> 6;
        Wt[(size_t)(rt0 + rr) * 512 + co0 + cc] = tile[cc][rr];
    }
}

// ---------------- conv 3x3 (pad 1) + bias + ReLU ----------------
// Block: 256 threads, tile = 64 cout x (4 rows x 64 cols). Grid (8, 16, 4).
// Thread: 4co x 4row x 4col = 64 acc. LDS demand ~64 B/cyc/CU (50% of peak).
__global__ __launch_bounds__(256, 2) void k_conv3x3(const float* __restrict__ x,
                                                    const float* __restrict__ wt,
                                                    const float* __restrict__ bias,
                                                    float* __restrict__ mid)
{
    __shared__ float sW[72 * 64];     // [ci*9+tap][co]
    __shared__ float sI[8][6][68];    // [ci][row y0-1..y0+4][col -1..66]
    const int t = threadIdx.x;
    const int n = blockIdx.z, co0 = blockIdx.x * 64, y0 = blockIdx.y * 4;
    const int tx = t & 15, ty = t >> 4;
    const int x0 = tx * 4;

    float acc[4][4][4];   // [c][r][j]
    #pragma unroll
    for (int c = 0; c < 4; ++c)
        #pragma unroll
        for (int r = 0; r < 4; ++r)
            #pragma unroll
            for (int j = 0; j < 4; ++j) acc[c][r][j] = 0.f;

    for (int ci0 = 0; ci0 < 512; ci0 += 8) {
        __syncthreads();
        // stage weights: 4608 floats, coalesced from transposed layout
        #pragma unroll
        for (int l = 0; l < 18; ++l) {
            int i = l * 256 + t;
            int tc = i >> 6, co = i & 63;
            sW[i] = wt[(size_t)(ci0 * 9 + tc) * 512 + co0 + co];
        }
        // stage input rows y0-1..y0+4 for 8 channels: 8*6*64 = 3072 floats
        #pragma unroll
        for (int l = 0; l < 12; ++l) {
            int i = l * 256 + t;
            int ci = i / 384;
            int rem = i - ci * 384;
            int r = rem >> 6, col = rem & 63;
            int gy = y0 + r - 1;
            float v = 0.f;
            if (gy >= 0 && gy < HH)
                v = x[((size_t)(n * CIN + ci0 + ci) * HH + gy) * WW + col];
            sI[ci][r][col + 1] = v;
        }
        if (t < 192) {
            int ci = t / 24;
            int q = t - ci * 24;
            int r = q >> 2, pp = q & 3;
            int col = (pp == 0) ? 0 : (64 + pp);
            sI[ci][r][col] = 0.f;
        }
        __syncthreads();

        #pragma unroll 2
        for (int ci = 0; ci < 8; ++ci) {
            float row[6][6];
            #pragma unroll
            for (int r = 0; r < 6; ++r)
                #pragma unroll
                for (int j = 0; j < 6; ++j) row[r][j] = sI[ci][r][x0 + j];
            #pragma unroll
            for (int ky = 0; ky < 3; ++ky) {
                float wv[3][4];
                #pragma unroll
                for (int kx = 0; kx < 3; ++kx)
                    #pragma unroll
                    for (int c = 0; c < 4; ++c)
                        wv[kx][c] = sW[(ci * 9 + ky * 3 + kx) * 64 + ty * 4 + c];
                #pragma unroll
                for (int kx = 0; kx < 3; ++kx)
                    #pragma unroll
                    for (int c = 0; c < 4; ++c)
                        #pragma unroll
                        for (int r = 0; r < 4; ++r)
                            #pragma unroll
                            for (int j = 0; j < 4; ++j)
                                acc[c][r][j] += wv[kx][c] * row[ky + r][kx + j];
            }
        }
    }
    // epilogue: bias + relu, float4 stores
    #pragma unroll
    for (int c = 0; c < 4; ++c) {
        float bv = bias[co0 + ty * 4 + c];
        #pragma unroll
        for (int r = 0; r < 4; ++r) {
            float4 v;
            v.x = fmaxf(acc[c][r][0] + bv, 0.f);
            v.y = fmaxf(acc[c][r][1] + bv, 0.f);
            v.z = fmaxf(acc[c][r][2] + bv, 0.f);
            v.w = fmaxf(acc[c][r][3] + bv, 0.f);
            *(float4*)&mid[((size_t)(n * 512 + co0 + ty * 4 + c) * HH + y0 + r) * WW + x0] = v;
        }
    }
}

// ---------------- head weights -> [ci][co] (co: 0..17 score, 18..53 loc, pad 64) ----
__global__ __launch_bounds__(256) void k_htrans(const float* __restrict__ Ws,
                                                const float* __restrict__ Wl,
                                                float* __restrict__ Wt2)
{
    int i = blockIdx.x * 256 + threadIdx.x;   // 512*64
    if (i >= 512 * 64) return;
    int ci = i >> 6, co = i & 63;
    float v = 0.f;
    if (co < 18) v = Ws[co * 512 + ci];
    else if (co < 54) v = Wl[(co - 18) * 512 + ci];
    Wt2[i] = v;
}

// ---------------- 1x1 heads as GEMM: sraw[n][co64][px4096] ----------------
__global__ __launch_bounds__(256) void k_hgemm(const float* __restrict__ mid,
                                               const float* __restrict__ Wt2,
                                               float* __restrict__ sraw)
{
    __shared__ float sM[32][64];   // [ci][px]
    __shared__ float sW2[32][64];  // [ci][co]
    const int t = threadIdx.x;
    const int px0 = blockIdx.x * 64, n = blockIdx.y;
    const int tx = t & 15, ty = t >> 4;

    float acc[4][4];
    #pragma unroll
    for (int c = 0; c < 4; ++c)
        #pragma unroll
        for (int j = 0; j < 4; ++j) acc[c][j] = 0.f;

    for (int ci0 = 0; ci0 < 512; ci0 += 32) {
        __syncthreads();
        #pragma unroll
        for (int l = 0; l < 8; ++l) {
            int i = l * 256 + t;
            int ci = i >> 6, px = i & 63;
            sM[ci][px] = mid[((size_t)n * 512 + ci0 + ci) * 4096 + px0 + px];
            sW2[ci][px] = Wt2[(size_t)(ci0 + ci) * 64 + px];
        }
        __syncthreads();
        #pragma unroll
        for (int ci = 0; ci < 32; ++ci) {
            float mv[4], wv[4];
            #pragma unroll
            for (int j = 0; j < 4; ++j) mv[j] = sM[ci][tx * 4 + j];
            #pragma unroll
            for (int c = 0; c < 4; ++c) wv[c] = sW2[ci][ty * 4 + c];
            #pragma unroll
            for (int c = 0; c < 4; ++c)
                #pragma unroll
                for (int j = 0; j < 4; ++j) acc[c][j] += wv[c] * mv[j];
        }
    }
    #pragma unroll
    for (int c = 0; c < 4; ++c) {
        float4 v = make_float4(acc[c][0], acc[c][1], acc[c][2], acc[c][3]);
        *(float4*)&sraw[((size_t)n * 64 + ty * 4 + c) * 4096 + px0 + tx * 4] = v;
    }
}

// ---------------- decode: softmax, loc2bbox, clip, keys, head outputs ----------------
__global__ __launch_bounds__(256) void k_decode(const float* __restrict__ sraw,
                                                const float* __restrict__ bsc,
                                                const float* __restrict__ blc,
                                                const int* __restrict__ ph,
                                                const int* __restrict__ pw,
                                                float* __restrict__ out,
                                                float* __restrict__ boxes,
                                                u32* __restrict__ key)
{
    int p = blockIdx.x * 256 + threadIdx.x;   // 0..16383
    int n = p >> 12, pi = p & 4095;
    int y = pi >> 6, xq = pi & 63;

    const float* S = sraw + (size_t)n * 64 * 4096 + pi;
    float* o0 = out + (size_t)n * 147456;
    float* o1 = out + OFF1 + (size_t)n * 73728;
    float IHf = (float)(*ph), IWf = (float)(*pw);

    #pragma unroll
    for (int a = 0; a < 9; ++a) {
        float s0 = S[(size_t)(2 * a) * 4096] + bsc[2 * a];
        float s1 = S[(size_t)(2 * a + 1) * 4096] + bsc[2 * a + 1];
        float dy = S[(size_t)(18 + 4 * a) * 4096] + blc[4 * a];
        float dx = S[(size_t)(19 + 4 * a) * 4096] + blc[4 * a + 1];
        float dh = S[(size_t)(20 + 4 * a) * 4096] + blc[4 * a + 2];
        float dw = S[(size_t)(21 + 4 * a) * 4096] + blc[4 * a + 3];

        o1[(pi * 9 + a) * 2 + 0] = s0;
        o1[(pi * 9 + a) * 2 + 1] = s1;
        o0[(pi * 9 + a) * 4 + 0] = dy;
        o0[(pi * 9 + a) * 4 + 1] = dx;
        o0[(pi * 9 + a) * 4 + 2] = dh;
        o0[(pi * 9 + a) * 4 + 3] = dw;

        // softmax fg (max-subtracted like jax.nn.softmax)
        float mm = fmaxf(s0, s1);
        float e0 = expf(s0 - mm), e1 = expf(s1 - mm);
        float fg = e1 / (e0 + e1);

        // anchor (base in f64 like numpy, then f32 add of exact shift)
        int ri = a / 3, si = a - ri * 3;
        double s = (double)(8 << si);
        double rr = (ri == 0) ? 0.5 : ((ri == 1) ? 1.0 : 2.0);
        double hh = 16.0 * s * sqrt(rr);
        double wd = 16.0 * s * sqrt(1.0 / rr);
        float a0 = (float)(8.0 - hh * 0.5) + (float)(y * 16);
        float a1 = (float)(8.0 - wd * 0.5) + (float)(xq * 16);
        float a2 = (float)(8.0 + hh * 0.5) + (float)(y * 16);
        float a3 = (float)(8.0 + wd * 0.5) + (float)(xq * 16);

        // loc2bbox
        float h = a2 - a0, w = a3 - a1;
        float cy = a0 + 0.5f * h, cx = a1 + 0.5f * w;
        float ncy = dy * h + cy, ncx = dx * w + cx;
        float nh = expf(dh) * h, nw = expf(dw) * w;
        float b0 = fminf(fmaxf(ncy - 0.5f * nh, 0.f), IHf);
        float b1 = fminf(fmaxf(ncx - 0.5f * nw, 0.f), IWf);
        float b2 = fminf(fmaxf(ncy + 0.5f * nh, 0.f), IHf);
        float b3 = fminf(fmaxf(ncx + 0.5f * nw, 0.f), IWf);

        bool ok = (b2 - b0 >= 16.0f) && (b3 - b1 >= 16.0f);
        float sc = ok ? fg : NEGV;

        int gi = n * HWA + pi * 9 + a;
        ((float4*)boxes)[gi] = make_float4(b0, b1, b2, b3);
        u32 u = __float_as_uint(sc);
        u32 kasc = (u & 0x80000000u) ? ~u : (u | 0x80000000u);
        key[gi] = ~kasc;   // ascending key == descending score
    }
}

// ---------------- anchors out + roi_indices + zero rois ----------------
__global__ void k_misc(float* __restrict__ out)
{
    int i = blockIdx.x * 256 + threadIdx.x;
    if (i < 4800) out[OFF2 + i] = 0.f;
    if (i < 1200) out[OFF3 + i] = (float)(i / 300);
    if (i < HWA) {
        int pi = i / 9, a = i - pi * 9;
        int y = pi >> 6, xq = pi & 63;
        int ri = a / 3, si = a - ri * 3;
        double s = (double)(8 << si);
        double rr = (ri == 0) ? 0.5 : ((ri == 1) ? 1.0 : 2.0);
        double hh = 16.0 * s * sqrt(rr);
        double wd = 16.0 * s * sqrt(1.0 / rr);
        out[OFF4 + i * 4 + 0] = (float)(8.0 - hh * 0.5) + (float)(y * 16);
        out[OFF4 + i * 4 + 1] = (float)(8.0 - wd * 0.5) + (float)(xq * 16);
        out[OFF4 + i * 4 + 2] = (float)(8.0 + hh * 0.5) + (float)(y * 16);
        out[OFF4 + i * 4 + 3] = (float)(8.0 + wd * 0.5) + (float)(xq * 16);
    }
}

// ---------------- exact rank-6000 radix select + compact ----------------
__global__ __launch_bounds__(1024) void k_select(const u32* __restrict__ key,
                                                 u64* __restrict__ cmp,
                                                 int* __restrict__ nvalid)
{
    __shared__ int hist[256];
    __shared__ u32 sPref;
    __shared__ int sR;
    __shared__ int cLess, cEq, cVal;
    int n = blockIdx.x, t = threadIdx.x;
    const u32* k0 = key + (size_t)n * HWA;

    u32 pref = 0, mask = 0;
    int R = PRE_NMS;
    for (int pass = 0; pass < 4; ++pass) {
        int shift = 24 - pass * 8;
        if (t < 256) hist[t] = 0;
        __syncthreads();
        for (int i = t; i < HWA; i += 1024) {
            u32 k = k0[i];
            if ((k & mask) == pref) atomicAdd(&hist[(k >> shift) & 255], 1);
        }
        __syncthreads();
        if (t == 0) {
            int cum = 0;
            for (int b = 0; b < 256; ++b) {
                int c = hist[b];
                if (cum + c >= R) { sPref = pref | ((u32)b << shift); sR = R - cum; break; }
                cum += c;
            }
        }
        __syncthreads();
        pref = sPref; R = sR; mask |= (0xFFu << shift);
        __syncthreads();
    }
    u32 T = pref;   // exact 6000th smallest key
    if (t == 0) { cLess = 0; cEq = 0; cVal = 0; }
    __syncthreads();
    for (int i = t; i < HWA; i += 1024) {
        u32 k = k0[i];
        if (k < NEGK) atomicAdd(&cVal, 1);
        if (k < T) {
            int p = atomicAdd(&cLess, 1);
            cmp[(size_t)n * 8192 + p] = ((u64)k << 32) | (u32)i;
        } else if (k == T) {
            int p = atomicAdd(&cEq, 1);
            if (p < R) cmp[(size_t)n * 8192 + (PRE_NMS - 1 - p)] = ((u64)k << 32) | (u32)i;
        }
    }
    for (int i = PRE_NMS + t; i < 8192; i += 1024) cmp[(size_t)n * 8192 + i] = ~0ull;
    __syncthreads();
    if (t == 0) nvalid[n] = cVal < PRE_NMS ? cVal : PRE_NMS;
}

// ---------------- bitonic sort of 8192 (key<<32|idx) in LDS ----------------
__global__ __launch_bounds__(1024) void k_sort(const u64* __restrict__ cmp,
                                               const float* __restrict__ boxes,
                                               float* __restrict__ boxesS)
{
    __shared__ u64 sK[8192];   // exactly 64 KiB
    int n = blockIdx.x, t = threadIdx.x;
    for (int i = t; i < 8192; i += 1024) sK[i] = cmp[(size_t)n * 8192 + i];
    for (unsigned k = 2; k <= 8192; k <<= 1) {
        for (unsigned j = k >> 1; j > 0; j >>= 1) {
            __syncthreads();
            #pragma unroll
            for (int v = 0; v < 8; ++v) {
                int i = v * 1024 + t;
                int ixj = i ^ (int)j;
                if (ixj > i) {
                    u64 a = sK[i], b = sK[ixj];
                    bool up = ((i & (int)k) == 0);
                    if (up ? (a > b) : (a < b)) { sK[i] = b; sK[ixj] = a; }
                }
            }
        }
    }
    __syncthreads();
    const float4* bsrc = (const float4*)boxes + (size_t)n * HWA;
    float4* bdst = (float4*)boxesS + (size_t)n * PRE_NMS;
    for (int i = t; i < PRE_NMS; i += 1024) {
        u32 idx = (u32)(sK[i] & 0xFFFFFFFFu);
        bdst[i] = bsrc[idx];
    }
}

// ---------------- IoU suppression bitmask: mask[n][i][w] ----------------
__global__ __launch_bounds__(64) void k_iou(const float* __restrict__ boxesS,
                                            u64* __restrict__ mask)
{
    __shared__ float4 cb[64];
    int w = blockIdx.x, ic = blockIdx.y, n = blockIdx.z;
    int t = threadIdx.x;
    const float4* B = (const float4*)boxesS + (size_t)n * PRE_NMS;
    int jc = w * 64 + t;
    cb[t] = (jc < PRE_NMS) ? B[jc] : make_float4(0.f, 0.f, 0.f, 0.f);
    __syncthreads();
    int i = ic * 64 + t;
    if (i >= PRE_NMS) return;
    float4 bb = B[i];
    float area1 = (bb.z - bb.x) * (bb.w - bb.y);
    u64 m = 0;
    #pragma unroll 8
    for (int j = 0; j < 64; ++j) {
        float4 o = cb[j];
        float ty_ = fmaxf(bb.x, o.x), tx_ = fmaxf(bb.y, o.y);
        float by_ = fminf(bb.z, o.z), bx_ = fminf(bb.w, o.w);
        float inter = fmaxf(by_ - ty_, 0.f) * fmaxf(bx_ - tx_, 0.f);
        float area2 = (o.z - o.x) * (o.w - o.y);
        float iou = inter / (area1 + area2 - inter + 1e-9f);
        if (iou > 0.7f) m |= (1ull << j);
    }
    mask[((size_t)n * PRE_NMS + i) * NWORD + w] = m;
}

// ---------------- greedy bitmask NMS scan (1 block / image) ----------------
__global__ __launch_bounds__(128) void k_nms2(const u64* __restrict__ mask,
                                              const int* __restrict__ nvalid,
                                              const float* __restrict__ boxesS,
                                              float* __restrict__ rois)
{
    __shared__ u64 rem[NWORD];
    __shared__ int sSel;
    int n = blockIdx.x, t = threadIdx.x;
    int nv = nvalid[n];
    if (t < NWORD) rem[t] = 0;
    __syncthreads();
    const u64* M = mask + (size_t)n * PRE_NMS * NWORD;
    const float4* B = (const float4*)boxesS + (size_t)n * PRE_NMS;
    int cnt = 0;
    int i = 0;   // live only on t==0
    while (cnt < POST_NMS) {
        if (t == 0) {
            int sel = -1;
            while (i < nv) {
                int w = i >> 6, b = i & 63;
                u64 avail = (~rem[w]) >> b;
                if (avail) {
                    int cand = i + __builtin_ctzll(avail);
                    if (cand < nv) sel = cand;
                    break;
                }
                i = (w + 1) << 6;
            }
            sSel = sel;
        }
        __syncthreads();
        int sel = sSel;
        if (sel < 0) break;
        if (t == 0) {
            float4 bb = B[sel];
            float* orow = rois + (size_t)(n * POST_NMS + cnt) * 4;
            orow[0] = bb.x; orow[1] = bb.y; orow[2] = bb.z; orow[3] = bb.w;
            i = sel + 1;
        }
        if (t < NWORD) rem[t] |= M[(size_t)sel * NWORD + t];
        cnt++;
        __syncthreads();
    }
}

extern "C" void kernel_launch(void* const* d_in, const int* in_sizes, int n_in,
                              void* d_out, int out_size, void* d_ws, size_t ws_size,
                              hipStream_t stream)
{
    const float* x  = (const float*)d_in[0];
    const float* W1 = (const float*)d_in[1];
    const float* b1 = (const float*)d_in[2];
    const float* Ws = (const float*)d_in[3];
    const float* bs = (const float*)d_in[4];
    const float* Wl = (const float*)d_in[5];
    const float* bl = (const float*)d_in[6];
    const int* ih   = (const int*)d_in[7];
    const int* iw   = (const int*)d_in[8];
    float* out = (float*)d_out;
    char* ws = (char*)d_ws;

    float* Wt     = (float*)(ws);                 //  9,437,184 B (dead after conv)
    float* mid    = (float*)(ws + 9437184);       // 33,554,432 B (dead after hgemm)
    float* boxes  = (float*)(ws + 42991616);      //  2,359,296 B
    u32*   key    = (u32*)  (ws + 45350912);      //    589,824 B
    u64*   cmp    = (u64*)  (ws + 45940736);      //    262,144 B
    float* boxesS = (float*)(ws + 46202880);      //    384,000 B
    int*   nval   = (int*)  (ws + 46586880);      //         16 B
    // reuse dead Wt region after conv:
    float* Wt2    = (float*)(ws);                 //    131,072 B [ci][co64]
    float* sraw   = (float*)(ws + 262144);        //  4,194,304 B [n][co64][px]
    // reuse dead mid region after hgemm:
    u64*   iomask = (u64*)  (ws + 9437184);       // 18,048,000 B

    k_transpose<<<dim3(72, 8), 256, 0, stream>>>(W1, Wt);
    k_conv3x3<<<dim3(8, 16, 4), 256, 0, stream>>>(x, Wt, b1, mid);
    k_htrans<<<128, 256, 0, stream>>>(Ws, Wl, Wt2);
    k_hgemm<<<dim3(64, 4), 256, 0, stream>>>(mid, Wt2, sraw);
    k_decode<<<64, 256, 0, stream>>>(sraw, bs, bl, ih, iw, out, boxes, key);
    k_misc<<<144, 256, 0, stream>>>(out);
    k_select<<<4, 1024, 0, stream>>>(key, cmp, nval);
    k_sort<<<4, 1024, 0, stream>>>(cmp, boxes, boxesS);
    k_iou<<<dim3(NWORD, NWORD, NIMG), 64, 0, stream>>>(boxesS, iomask);
    k_nms2<<<NIMG, 128, 0, stream>>>(iomask, nval, boxesS, out + OFF2);
}

// Round 5
// 1501.369 us; speedup vs baseline: 2.7865x; 1.0400x over previous
//
#include <hip/hip_runtime.h>
#include <math.h>

#define HH 64
#define WW 64
#define NIMG 4
#define CIN 512
#define AA 9
#define HWA (HH*WW*AA)          // 36864
#define PRE_NMS 6000
#define POST_NMS 300
#define NEGV (-1e10f)
#define NEGK 0xD01502F9u        // descending-order key of -1e10f
#define NWORD 94                // ceil(6000/64)

#define OFF1 589824             // rpn_scores
#define OFF2 884736             // rois
#define OFF3 889536             // roi_indices
#define OFF4 890736             // anchors

typedef unsigned int u32;
typedef unsigned long long u64;

__device__ __forceinline__ void gload_lds16(const float* g, float* l)
{
    __builtin_amdgcn_global_load_lds((const __attribute__((address_space(1))) void*)g,
                                     (__attribute__((address_space(3))) void*)l,
                                     16, 0, 0);
}

// ---------------- W transpose: W[co][ci][tap] -> Wt[ci*9+tap][co] ----------------
__global__ __launch_bounds__(256) void k_transpose(const float* __restrict__ Wsrc,
                                                   float* __restrict__ Wt)
{
    __shared__ float tile[64][65];
    int rt0 = blockIdx.x * 64;   // ci*9+tap tile (4608/64 = 72)
    int co0 = blockIdx.y * 64;   // co tile (512/64 = 8)
    int t = threadIdx.x;
    #pragma unroll
    for (int l = 0; l < 16; ++l) {
        int i = l * 256 + t;
        int rr = i & 63, cc = i >> 6;
        tile[cc][rr] = Wsrc[(size_t)(co0 + cc) * 4608 + rt0 + rr];
    }
    __syncthreads();
    #pragma unroll
    for (int l = 0; l < 16; ++l) {
        int i = l * 256 + t;
        int cc = i & 63, rr = i >> 6;
        Wt[(size_t)(rt0 + rr) * 512 + co0 + cc] = tile[cc][rr];
    }
}

// ---------------- conv 3x3 (pad 1) + bias + ReLU — async double-buffered ----------
// Block 256: tile 64 cout x (4 rows x 64 cols). Grid (8, 16, 4) = 512 = 2 blocks/CU.
// Staging via global_load_lds (16B/lane) into double-buffered LDS; 1 barrier/iter.
__global__ __launch_bounds__(256, 2) void k_conv3x3(const float* __restrict__ x,
                                                    const float* __restrict__ wt,
                                                    const float* __restrict__ bias,
                                                    float* __restrict__ mid)
{
    __shared__ float sW[2][4608];      // [buf][(ci*9+tap)*64 + co]
    __shared__ float sI[2][8][6][64];  // [buf][ci][row y0-1..y0+4][col], no pad
    const int t = threadIdx.x;
    const int n = blockIdx.z, co0 = blockIdx.x * 64, y0 = blockIdx.y * 4;
    const int tx = t & 15, ty = t >> 4;
    const int x0 = tx * 4;
    const int wave = t >> 6, lane = t & 63;

    // zero the vertical-halo rows that masked prefetch lanes never write
    if (y0 == 0) {
        #pragma unroll
        for (int l = 0; l < 4; ++l) {
            int i = l * 256 + t;                 // 1024 = 2 buf * 8 ci * 64 col
            sI[i >> 9][(i >> 6) & 7][0][i & 63] = 0.f;
        }
    }
    if (y0 == 60) {
        #pragma unroll
        for (int l = 0; l < 4; ++l) {
            int i = l * 256 + t;
            sI[i >> 9][(i >> 6) & 7][5][i & 63] = 0.f;
        }
    }

    float acc[4][4][4];   // [c][r][j]
    #pragma unroll
    for (int c = 0; c < 4; ++c)
        #pragma unroll
        for (int r = 0; r < 4; ++r)
            #pragma unroll
            for (int j = 0; j < 4; ++j) acc[c][r][j] = 0.f;

    // ---- prefetch helper (inlined twice) ----
    auto prefetch = [&](int ci0, int buf) {
        // sW: 18 chunks x 256 floats, wave-uniform chunk base
        #pragma unroll
        for (int k = wave; k < 18; k += 4) {
            int tap = k * 4 + (lane >> 4);
            int co  = (lane & 15) * 4;
            gload_lds16(&wt[(size_t)(ci0 * 9 + tap) * 512 + co0 + co], &sW[buf][k * 256]);
        }
        // sI: 12 chunks x 256 floats
        #pragma unroll
        for (int k = wave; k < 12; k += 4) {
            int rf = k * 4 + (lane >> 4);        // 0..47 = ci*6 + r
            int ci = rf / 6, r = rf - ci * 6;
            int col = (lane & 15) * 4;
            int gy = y0 + r - 1;
            if ((unsigned)gy < 64u)
                gload_lds16(&x[((size_t)(n * CIN + ci0 + ci) * HH + gy) * WW + col],
                            &sI[buf][0][0][0] + k * 256);
        }
    };

    prefetch(0, 0);

    const int xm = (tx == 0) ? 0 : x0 - 1;      // clamped; value replaced by 0 below
    const int xp = (tx == 15) ? 63 : x0 + 4;

    for (int it = 0; it < 64; ++it) {
        const int cur = it & 1;
        __syncthreads();                         // drains vmcnt -> buf[cur] ready
        if (it + 1 < 64) prefetch((it + 1) * 8, 1 - cur);

        #pragma unroll 2
        for (int ci = 0; ci < 8; ++ci) {
            float row[6][6];
            #pragma unroll
            for (int r = 0; r < 6; ++r) {
                row[r][0] = (tx == 0) ? 0.f : sI[cur][ci][r][xm];
                float4 q = *(const float4*)&sI[cur][ci][r][x0];
                row[r][1] = q.x; row[r][2] = q.y; row[r][3] = q.z; row[r][4] = q.w;
                row[r][5] = (tx == 15) ? 0.f : sI[cur][ci][r][xp];
            }
            #pragma unroll
            for (int ky = 0; ky < 3; ++ky) {
                float wv[3][4];
                #pragma unroll
                for (int kx = 0; kx < 3; ++kx)
                    #pragma unroll
                    for (int c = 0; c < 4; ++c)
                        wv[kx][c] = sW[cur][(ci * 9 + ky * 3 + kx) * 64 + ty * 4 + c];
                #pragma unroll
                for (int kx = 0; kx < 3; ++kx)
                    #pragma unroll
                    for (int c = 0; c < 4; ++c)
                        #pragma unroll
                        for (int r = 0; r < 4; ++r)
                            #pragma unroll
                            for (int j = 0; j < 4; ++j)
                                acc[c][r][j] += wv[kx][c] * row[ky + r][kx + j];
            }
        }
    }
    // epilogue: bias + relu, float4 stores
    #pragma unroll
    for (int c = 0; c < 4; ++c) {
        float bv = bias[co0 + ty * 4 + c];
        #pragma unroll
        for (int r = 0; r < 4; ++r) {
            float4 v;
            v.x = fmaxf(acc[c][r][0] + bv, 0.f);
            v.y = fmaxf(acc[c][r][1] + bv, 0.f);
            v.z = fmaxf(acc[c][r][2] + bv, 0.f);
            v.w = fmaxf(acc[c][r][3] + bv, 0.f);
            *(float4*)&mid[((size_t)(n * 512 + co0 + ty * 4 + c) * HH + y0 + r) * WW + x0] = v;
        }
    }
}

// ---------------- head weights -> [ci][co] (co: 0..17 score, 18..53 loc, pad 64) ----
__global__ __launch_bounds__(256) void k_htrans(const float* __restrict__ Ws,
                                                const float* __restrict__ Wl,
                                                float* __restrict__ Wt2)
{
    int i = blockIdx.x * 256 + threadIdx.x;   // 512*64
    if (i >= 512 * 64) return;
    int ci = i >> 6, co = i & 63;
    float v = 0.f;
    if (co < 18) v = Ws[co * 512 + ci];
    else if (co < 54) v = Wl[(co - 18) * 512 + ci];
    Wt2[i] = v;
}

// ---------------- 1x1 heads as GEMM: sraw[n][co64][px4096] ----------------
__global__ __launch_bounds__(256) void k_hgemm(const float* __restrict__ mid,
                                               const float* __restrict__ Wt2,
                                               float* __restrict__ sraw)
{
    __shared__ float sM[32][64];   // [ci][px]
    __shared__ float sW2[32][64];  // [ci][co]
    const int t = threadIdx.x;
    const int px0 = blockIdx.x * 64, n = blockIdx.y;
    const int tx = t & 15, ty = t >> 4;

    float acc[4][4];
    #pragma unroll
    for (int c = 0; c < 4; ++c)
        #pragma unroll
        for (int j = 0; j < 4; ++j) acc[c][j] = 0.f;

    for (int ci0 = 0; ci0 < 512; ci0 += 32) {
        __syncthreads();
        #pragma unroll
        for (int l = 0; l < 8; ++l) {
            int i = l * 256 + t;
            int ci = i >> 6, px = i & 63;
            sM[ci][px] = mid[((size_t)n * 512 + ci0 + ci) * 4096 + px0 + px];
            sW2[ci][px] = Wt2[(size_t)(ci0 + ci) * 64 + px];
        }
        __syncthreads();
        #pragma unroll
        for (int ci = 0; ci < 32; ++ci) {
            float mv[4], wv[4];
            #pragma unroll
            for (int j = 0; j < 4; ++j) mv[j] = sM[ci][tx * 4 + j];
            #pragma unroll
            for (int c = 0; c < 4; ++c) wv[c] = sW2[ci][ty * 4 + c];
            #pragma unroll
            for (int c = 0; c < 4; ++c)
                #pragma unroll
                for (int j = 0; j < 4; ++j) acc[c][j] += wv[c] * mv[j];
        }
    }
    #pragma unroll
    for (int c = 0; c < 4; ++c) {
        float4 v = make_float4(acc[c][0], acc[c][1], acc[c][2], acc[c][3]);
        *(float4*)&sraw[((size_t)n * 64 + ty * 4 + c) * 4096 + px0 + tx * 4] = v;
    }
}

// ---------------- decode: softmax, loc2bbox, clip, keys, head outputs ----------------
__global__ __launch_bounds__(256) void k_decode(const float* __restrict__ sraw,
                                                const float* __restrict__ bsc,
                                                const float* __restrict__ blc,
                                                const int* __restrict__ ph,
                                                const int* __restrict__ pw,
                                                float* __restrict__ out,
                                                float* __restrict__ boxes,
                                                u32* __restrict__ key)
{
    int p = blockIdx.x * 256 + threadIdx.x;   // 0..16383
    int n = p >> 12, pi = p & 4095;
    int y = pi >> 6, xq = pi & 63;

    const float* S = sraw + (size_t)n * 64 * 4096 + pi;
    float* o0 = out + (size_t)n * 147456;
    float* o1 = out + OFF1 + (size_t)n * 73728;
    float IHf = (float)(*ph), IWf = (float)(*pw);

    #pragma unroll
    for (int a = 0; a < 9; ++a) {
        float s0 = S[(size_t)(2 * a) * 4096] + bsc[2 * a];
        float s1 = S[(size_t)(2 * a + 1) * 4096] + bsc[2 * a + 1];
        float dy = S[(size_t)(18 + 4 * a) * 4096] + blc[4 * a];
        float dx = S[(size_t)(19 + 4 * a) * 4096] + blc[4 * a + 1];
        float dh = S[(size_t)(20 + 4 * a) * 4096] + blc[4 * a + 2];
        float dw = S[(size_t)(21 + 4 * a) * 4096] + blc[4 * a + 3];

        o1[(pi * 9 + a) * 2 + 0] = s0;
        o1[(pi * 9 + a) * 2 + 1] = s1;
        o0[(pi * 9 + a) * 4 + 0] = dy;
        o0[(pi * 9 + a) * 4 + 1] = dx;
        o0[(pi * 9 + a) * 4 + 2] = dh;
        o0[(pi * 9 + a) * 4 + 3] = dw;

        // softmax fg (max-subtracted like jax.nn.softmax)
        float mm = fmaxf(s0, s1);
        float e0 = expf(s0 - mm), e1 = expf(s1 - mm);
        float fg = e1 / (e0 + e1);

        // anchor (base in f64 like numpy, then f32 add of exact shift)
        int ri = a / 3, si = a - ri * 3;
        double s = (double)(8 << si);
        double rr = (ri == 0) ? 0.5 : ((ri == 1) ? 1.0 : 2.0);
        double hh = 16.0 * s * sqrt(rr);
        double wd = 16.0 * s * sqrt(1.0 / rr);
        float a0 = (float)(8.0 - hh * 0.5) + (float)(y * 16);
        float a1 = (float)(8.0 - wd * 0.5) + (float)(xq * 16);
        float a2 = (float)(8.0 + hh * 0.5) + (float)(y * 16);
        float a3 = (float)(8.0 + wd * 0.5) + (float)(xq * 16);

        // loc2bbox
        float h = a2 - a0, w = a3 - a1;
        float cy = a0 + 0.5f * h, cx = a1 + 0.5f * w;
        float ncy = dy * h + cy, ncx = dx * w + cx;
        float nh = expf(dh) * h, nw = expf(dw) * w;
        float b0 = fminf(fmaxf(ncy - 0.5f * nh, 0.f), IHf);
        float b1 = fminf(fmaxf(ncx - 0.5f * nw, 0.f), IWf);
        float b2 = fminf(fmaxf(ncy + 0.5f * nh, 0.f), IHf);
        float b3 = fminf(fmaxf(ncx + 0.5f * nw, 0.f), IWf);

        bool ok = (b2 - b0 >= 16.0f) && (b3 - b1 >= 16.0f);
        float sc = ok ? fg : NEGV;

        int gi = n * HWA + pi * 9 + a;
        ((float4*)boxes)[gi] = make_float4(b0, b1, b2, b3);
        u32 u = __float_as_uint(sc);
        u32 kasc = (u & 0x80000000u) ? ~u : (u | 0x80000000u);
        key[gi] = ~kasc;   // ascending key == descending score
    }
}

// ---------------- anchors out + roi_indices + zero rois ----------------
__global__ void k_misc(float* __restrict__ out)
{
    int i = blockIdx.x * 256 + threadIdx.x;
    if (i < 4800) out[OFF2 + i] = 0.f;
    if (i < 1200) out[OFF3 + i] = (float)(i / 300);
    if (i < HWA) {
        int pi = i / 9, a = i - pi * 9;
        int y = pi >> 6, xq = pi & 63;
        int ri = a / 3, si = a - ri * 3;
        double s = (double)(8 << si);
        double rr = (ri == 0) ? 0.5 : ((ri == 1) ? 1.0 : 2.0);
        double hh = 16.0 * s * sqrt(rr);
        double wd = 16.0 * s * sqrt(1.0 / rr);
        out[OFF4 + i * 4 + 0] = (float)(8.0 - hh * 0.5) + (float)(y * 16);
        out[OFF4 + i * 4 + 1] = (float)(8.0 - wd * 0.5) + (float)(xq * 16);
        out[OFF4 + i * 4 + 2] = (float)(8.0 + hh * 0.5) + (float)(y * 16);
        out[OFF4 + i * 4 + 3] = (float)(8.0 + wd * 0.5) + (float)(xq * 16);
    }
}

// ---------------- exact rank-6000 radix select + compact ----------------
__global__ __launch_bounds__(1024) void k_select(const u32* __restrict__ key,
                                                 u64* __restrict__ cmp,
                                                 int* __restrict__ nvalid)
{
    __shared__ int hist[256];
    __shared__ u32 sPref;
    __shared__ int sR;
    __shared__ int cLess, cEq, cVal;
    int n = blockIdx.x, t = threadIdx.x;
    const u32* k0 = key + (size_t)n * HWA;

    u32 pref = 0, mask = 0;
    int R = PRE_NMS;
    for (int pass = 0; pass < 4; ++pass) {
        int shift = 24 - pass * 8;
        if (t < 256) hist[t] = 0;
        __syncthreads();
        for (int i = t; i < HWA; i += 1024) {
            u32 k = k0[i];
            if ((k & mask) == pref) atomicAdd(&hist[(k >> shift) & 255], 1);
        }
        __syncthreads();
        if (t == 0) {
            int cum = 0;
            for (int b = 0; b < 256; ++b) {
                int c = hist[b];
                if (cum + c >= R) { sPref = pref | ((u32)b << shift); sR = R - cum; break; }
                cum += c;
            }
        }
        __syncthreads();
        pref = sPref; R = sR; mask |= (0xFFu << shift);
        __syncthreads();
    }
    u32 T = pref;   // exact 6000th smallest key
    if (t == 0) { cLess = 0; cEq = 0; cVal = 0; }
    __syncthreads();
    for (int i = t; i < HWA; i += 1024) {
        u32 k = k0[i];
        if (k < NEGK) atomicAdd(&cVal, 1);
        if (k < T) {
            int p = atomicAdd(&cLess, 1);
            cmp[(size_t)n * 8192 + p] = ((u64)k << 32) | (u32)i;
        } else if (k == T) {
            int p = atomicAdd(&cEq, 1);
            if (p < R) cmp[(size_t)n * 8192 + (PRE_NMS - 1 - p)] = ((u64)k << 32) | (u32)i;
        }
    }
    for (int i = PRE_NMS + t; i < 8192; i += 1024) cmp[(size_t)n * 8192 + i] = ~0ull;
    __syncthreads();
    if (t == 0) nvalid[n] = cVal < PRE_NMS ? cVal : PRE_NMS;
}

// ---------------- bitonic sort of 8192 (key<<32|idx) in LDS ----------------
__global__ __launch_bounds__(1024) void k_sort(const u64* __restrict__ cmp,
                                               const float* __restrict__ boxes,
                                               float* __restrict__ boxesS)
{
    __shared__ u64 sK[8192];   // exactly 64 KiB
    int n = blockIdx.x, t = threadIdx.x;
    for (int i = t; i < 8192; i += 1024) sK[i] = cmp[(size_t)n * 8192 + i];
    for (unsigned k = 2; k <= 8192; k <<= 1) {
        for (unsigned j = k >> 1; j > 0; j >>= 1) {
            __syncthreads();
            #pragma unroll
            for (int v = 0; v < 8; ++v) {
                int i = v * 1024 + t;
                int ixj = i ^ (int)j;
                if (ixj > i) {
                    u64 a = sK[i], b = sK[ixj];
                    bool up = ((i & (int)k) == 0);
                    if (up ? (a > b) : (a < b)) { sK[i] = b; sK[ixj] = a; }
                }
            }
        }
    }
    __syncthreads();
    const float4* bsrc = (const float4*)boxes + (size_t)n * HWA;
    float4* bdst = (float4*)boxesS + (size_t)n * PRE_NMS;
    for (int i = t; i < PRE_NMS; i += 1024) {
        u32 idx = (u32)(sK[i] & 0xFFFFFFFFu);
        bdst[i] = bsrc[idx];
    }
}

// ---------------- IoU suppression bitmask: mask[n][i][w] ----------------
__global__ __launch_bounds__(64) void k_iou(const float* __restrict__ boxesS,
                                            u64* __restrict__ mask)
{
    __shared__ float4 cb[64];
    int w = blockIdx.x, ic = blockIdx.y, n = blockIdx.z;
    int t = threadIdx.x;
    const float4* B = (const float4*)boxesS + (size_t)n * PRE_NMS;
    int jc = w * 64 + t;
    cb[t] = (jc < PRE_NMS) ? B[jc] : make_float4(0.f, 0.f, 0.f, 0.f);
    __syncthreads();
    int i = ic * 64 + t;
    if (i >= PRE_NMS) return;
    float4 bb = B[i];
    float area1 = (bb.z - bb.x) * (bb.w - bb.y);
    u64 m = 0;
    #pragma unroll 8
    for (int j = 0; j < 64; ++j) {
        float4 o = cb[j];
        float ty_ = fmaxf(bb.x, o.x), tx_ = fmaxf(bb.y, o.y);
        float by_ = fminf(bb.z, o.z), bx_ = fminf(bb.w, o.w);
        float inter = fmaxf(by_ - ty_, 0.f) * fmaxf(bx_ - tx_, 0.f);
        float area2 = (o.z - o.x) * (o.w - o.y);
        float iou = inter / (area1 + area2 - inter + 1e-9f);
        if (iou > 0.7f) m |= (1ull << j);
    }
    mask[((size_t)n * PRE_NMS + i) * NWORD + w] = m;
}

// ---------------- greedy bitmask NMS: single wave, zero barriers ----------------
__global__ __launch_bounds__(64) void k_nms3(const u64* __restrict__ mask,
                                             const int* __restrict__ nvalid,
                                             const float* __restrict__ boxesS,
                                             float* __restrict__ rois)
{
    int n = blockIdx.x, lane = threadIdx.x;
    int nv = nvalid[n];
    const u64* M = mask + (size_t)n * PRE_NMS * NWORD;
    const float4* B = (const float4*)boxesS + (size_t)n * PRE_NMS;

    // validity masks for this lane's two words (word lane, word 64+lane)
    auto vmask = [&](int w) -> u64 {
        int lo = w * 64;
        if (nv >= lo + 64) return ~0ull;
        if (nv <= lo) return 0ull;
        return (1ull << (nv - lo)) - 1ull;
    };
    u64 vm0 = vmask(lane);
    u64 vm1 = (lane < NWORD - 64) ? vmask(64 + lane) : 0ull;
    u64 rem0 = 0, rem1 = 0;

    int cnt = 0;
    while (cnt < POST_NMS) {
        u64 c0 = (~rem0) & vm0;
        u64 c1 = (~rem1) & vm1;
        int sel;
        u64 b0 = __ballot(c0 != 0);
        if (b0) {
            int l = __builtin_ctzll(b0);
            u64 w = __shfl(c0, l);
            sel = l * 64 + __builtin_ctzll(w);
        } else {
            u64 b1 = __ballot(c1 != 0);
            if (!b1) break;
            int l = __builtin_ctzll(b1);
            u64 w = __shfl(c1, l);
            sel = (64 + l) * 64 + __builtin_ctzll(w);
        }
        if (lane == 0) {
            float4 bb = B[sel];
            float* orow = rois + (size_t)(n * POST_NMS + cnt) * 4;
            orow[0] = bb.x; orow[1] = bb.y; orow[2] = bb.z; orow[3] = bb.w;
        }
        const u64* Mr = M + (size_t)sel * NWORD;
        rem0 |= Mr[lane];
        if (lane < NWORD - 64) rem1 |= Mr[64 + lane];
        cnt++;
    }
}

extern "C" void kernel_launch(void* const* d_in, const int* in_sizes, int n_in,
                              void* d_out, int out_size, void* d_ws, size_t ws_size,
                              hipStream_t stream)
{
    const float* x  = (const float*)d_in[0];
    const float* W1 = (const float*)d_in[1];
    const float* b1 = (const float*)d_in[2];
    const float* Ws = (const float*)d_in[3];
    const float* bs = (const float*)d_in[4];
    const float* Wl = (const float*)d_in[5];
    const float* bl = (const float*)d_in[6];
    const int* ih   = (const int*)d_in[7];
    const int* iw   = (const int*)d_in[8];
    float* out = (float*)d_out;
    char* ws = (char*)d_ws;

    float* Wt     = (float*)(ws);                 //  9,437,184 B (dead after conv)
    float* mid    = (float*)(ws + 9437184);       // 33,554,432 B (dead after hgemm)
    float* boxes  = (float*)(ws + 42991616);      //  2,359,296 B
    u32*   key    = (u32*)  (ws + 45350912);      //    589,824 B
    u64*   cmp    = (u64*)  (ws + 45940736);      //    262,144 B
    float* boxesS = (float*)(ws + 46202880);      //    384,000 B
    int*   nval   = (int*)  (ws + 46586880);      //         16 B
    // reuse dead Wt region after conv:
    float* Wt2    = (float*)(ws);                 //    131,072 B [ci][co64]
    float* sraw   = (float*)(ws + 262144);        //  4,194,304 B [n][co64][px]
    // reuse dead mid region after hgemm:
    u64*   iomask = (u64*)  (ws + 9437184);       // 18,048,000 B

    k_transpose<<<dim3(72, 8), 256, 0, stream>>>(W1, Wt);
    k_conv3x3<<<dim3(8, 16, 4), 256, 0, stream>>>(x, Wt, b1, mid);
    k_htrans<<<128, 256, 0, stream>>>(Ws, Wl, Wt2);
    k_hgemm<<<dim3(64, 4), 256, 0, stream>>>(mid, Wt2, sraw);
    k_decode<<<64, 256, 0, stream>>>(sraw, bs, bl, ih, iw, out, boxes, key);
    k_misc<<<144, 256, 0, stream>>>(out);
    k_select<<<4, 1024, 0, stream>>>(key, cmp, nval);
    k_sort<<<4, 1024, 0, stream>>>(cmp, boxes, boxesS);
    k_iou<<<dim3(NWORD, NWORD, NIMG), 64, 0, stream>>>(boxesS, iomask);
    k_nms3<<<NIMG, 64, 0, stream>>>(iomask, nval, boxesS, out + OFF2);
}

// Round 6
// 1133.288 us; speedup vs baseline: 3.6915x; 1.3248x over previous
//
#include <hip/hip_runtime.h>
#include <math.h>

#define HH 64
#define WW 64
#define NIMG 4
#define CIN 512
#define AA 9
#define HWA (HH*WW*AA)          // 36864
#define PRE_NMS 6000
#define POST_NMS 300
#define NEGV (-1e10f)
#define NEGK 0xD01502F9u        // descending-order key of -1e10f
#define NWORD 94                // ceil(6000/64)

#define OFF1 589824             // rpn_scores
#define OFF2 884736             // rois
#define OFF3 889536             // roi_indices
#define OFF4 890736             // anchors

typedef unsigned int u32;
typedef unsigned long long u64;
typedef _Float16 f16;
typedef _Float16 half8 __attribute__((ext_vector_type(8)));
typedef float f32x4 __attribute__((ext_vector_type(4)));

__device__ __forceinline__ void gload_lds16(const void* g, void* l)
{
    __builtin_amdgcn_global_load_lds((const __attribute__((address_space(1))) void*)g,
                                     (__attribute__((address_space(3))) void*)l,
                                     16, 0, 0);
}

// ---------------- prep: x[n][ci][y][xc] f32 -> x_t[n][y][xc][ci] fp16 hi/lo ----------
__global__ __launch_bounds__(256) void k_prep_x(const float* __restrict__ x,
                                                f16* __restrict__ xh,
                                                f16* __restrict__ xl)
{
    __shared__ float tile[64][65];
    int ci0 = blockIdx.x * 64, y = blockIdx.y, n = blockIdx.z;
    int t = threadIdx.x;
    #pragma unroll
    for (int l = 0; l < 16; ++l) {
        int idx = l * 256 + t;
        int cc = idx >> 6, xc = idx & 63;
        tile[cc][xc] = x[((size_t)(n * CIN + ci0 + cc) * HH + y) * WW + xc];
    }
    __syncthreads();
    #pragma unroll
    for (int l = 0; l < 16; ++l) {
        int idx = l * 256 + t;
        int xc = idx >> 6, cc = idx & 63;
        float v = tile[cc][xc];
        f16 hi = (f16)v;
        f16 lo = (f16)(v - (float)hi);
        size_t o = ((size_t)(n * 64 + y) * 64 + xc) * 512 + ci0 + cc;
        xh[o] = hi; xl[o] = lo;
    }
}

// ---------------- prep: W1[co][ci][tap] f32 -> W2[tap][co][ci] fp16 hi/lo ----------
__global__ __launch_bounds__(256) void k_prep_w(const float* __restrict__ W1,
                                                f16* __restrict__ wh,
                                                f16* __restrict__ wl)
{
    int idx = blockIdx.x * 256 + threadIdx.x;   // 512*512
    int co = idx >> 9, ci = idx & 511;
    #pragma unroll
    for (int tap = 0; tap < 9; ++tap) {
        float v = W1[(size_t)idx * 9 + tap];
        f16 hi = (f16)v;
        f16 lo = (f16)(v - (float)hi);
        size_t o = ((size_t)tap * 512 + co) * 512 + ci;
        wh[o] = hi; wl[o] = lo;
    }
}

// ---------------- conv3x3 via MFMA fp16x3 implicit GEMM ----------------
// Block 256 (4 waves): out tile = 64 cout x (2 y-rows x 64 x). Grid (8, 32, 4).
// A = W[tap][co][ci] (global VGPR loads), B = x_t staged in LDS [row][col][ci32].
// acc: wave = 4 m-tiles(16co) x 2 n-tiles(16px). 3 MFMA passes: ah*bh+ah*bl+al*bh.
__global__ __launch_bounds__(256, 2) void k_conv_mfma(const f16* __restrict__ xh,
                                                      const f16* __restrict__ xl,
                                                      const f16* __restrict__ wh,
                                                      const f16* __restrict__ wl,
                                                      const float* __restrict__ bias,
                                                      float* __restrict__ mid)
{
    __shared__ f16 sX[2][2][4][64][32];   // [buf][plane][row][col][ci] = 65536 B
    const int t = threadIdx.x;
    const int co0 = blockIdx.x * 64, yb = blockIdx.y, n = blockIdx.z;
    const int y0 = yb * 2;
    const int wv = t >> 6, lane = t & 63;
    const int q = lane >> 4, li = lane & 15;
    const int yw = wv >> 1;               // which of the 2 y rows this wave covers
    const int xbase = (wv & 1) * 32;      // pixel x start (nt*16 added)

    // pre-zero vertical halo rows (rows never written by masked prefetch)
    if (yb == 0) {
        for (int k = t; k < 4096; k += 256) {
            int bp = k >> 10, rem = k & 1023;
            ((u32*)&sX[bp >> 1][bp & 1][0][0][0])[rem] = 0;
        }
    }
    if (yb == 31) {
        for (int k = t; k < 4096; k += 256) {
            int bp = k >> 10, rem = k & 1023;
            ((u32*)&sX[bp >> 1][bp & 1][3][0][0])[rem] = 0;
        }
    }

    f32x4 acc[4][2];
    #pragma unroll
    for (int mt = 0; mt < 4; ++mt)
        #pragma unroll
        for (int nt = 0; nt < 2; ++nt)
            acc[mt][nt] = (f32x4){0.f, 0.f, 0.f, 0.f};

    // staging: 32 insts x 64 lanes x 16B = both planes, 4 rows, 64 cols, 32 ci
    auto prefetch = [&](int ci0, int buf) {
        #pragma unroll
        for (int m = 0; m < 8; ++m) {
            int k2 = wv * 8 + m;               // 0..31, wave-uniform
            int plane = k2 >> 4;
            int row = (k2 >> 2) & 3;
            int gy = y0 - 1 + row;
            if ((unsigned)gy < 64u) {
                int col = ((k2 & 3) << 4) + (lane >> 2);
                int s = lane & 3;
                const f16* src = (plane ? xl : xh) +
                    (((size_t)(n * 64 + gy) * 64 + col) * 512 + ci0 + s * 8);
                f16* dst = &sX[0][0][0][0][0] + (size_t)buf * 16384 + k2 * 512 + lane * 8;
                gload_lds16(src, dst);
            }
        }
    };

    prefetch(0, 0);

    const half8 zero8 = {(f16)0, (f16)0, (f16)0, (f16)0, (f16)0, (f16)0, (f16)0, (f16)0};
    half8 wa[2][4], wn[2][4];

    for (int chunk = 0; chunk < 16; ++chunk) {
        const int cur = chunk & 1;
        const int ci0 = chunk * 32;
        __syncthreads();                       // buf[cur] ready (vmcnt drain)
        if (chunk + 1 < 16) prefetch(ci0 + 32, 1 - cur);

        // load W frags for tap 0
        {
            size_t base = ((size_t)(co0 + li) * 512 + ci0 + q * 8);
            #pragma unroll
            for (int mt = 0; mt < 4; ++mt) {
                wa[0][mt] = *(const half8*)(wh + base + (size_t)mt * 16 * 512);
                wa[1][mt] = *(const half8*)(wl + base + (size_t)mt * 16 * 512);
            }
        }

        #pragma unroll
        for (int tap = 0; tap < 9; ++tap) {
            if (tap + 1 < 9) {                 // pipeline next tap's W frags
                size_t base = ((size_t)((tap + 1) * 512 + co0 + li) * 512 + ci0 + q * 8);
                #pragma unroll
                for (int mt = 0; mt < 4; ++mt) {
                    wn[0][mt] = *(const half8*)(wh + base + (size_t)mt * 16 * 512);
                    wn[1][mt] = *(const half8*)(wl + base + (size_t)mt * 16 * 512);
                }
            }
            const int ky = tap / 3, kx = tap - ky * 3;
            const int row = yw + ky;           // staged row index (rows y0-1..y0+2)

            half8 bh[2], bl[2];
            #pragma unroll
            for (int nt = 0; nt < 2; ++nt) {
                int xc = xbase + nt * 16 + li;
                int colr = xc + kx - 1;
                bool oob = (colr < 0) || (colr > 63);
                int colc = oob ? 0 : colr;
                const f16* ph = &sX[cur][0][row][colc][q * 8];
                bh[nt] = *(const half8*)ph;
                bl[nt] = *(const half8*)(ph + 8192);   // plane stride = 8192 f16
                if (oob) { bh[nt] = zero8; bl[nt] = zero8; }
            }
            // pass 1: ah*bh
            #pragma unroll
            for (int mt = 0; mt < 4; ++mt)
                #pragma unroll
                for (int nt = 0; nt < 2; ++nt)
                    acc[mt][nt] = __builtin_amdgcn_mfma_f32_16x16x32_f16(wa[0][mt], bh[nt], acc[mt][nt], 0, 0, 0);
            // pass 2: ah*bl
            #pragma unroll
            for (int mt = 0; mt < 4; ++mt)
                #pragma unroll
                for (int nt = 0; nt < 2; ++nt)
                    acc[mt][nt] = __builtin_amdgcn_mfma_f32_16x16x32_f16(wa[0][mt], bl[nt], acc[mt][nt], 0, 0, 0);
            // pass 3: al*bh
            #pragma unroll
            for (int mt = 0; mt < 4; ++mt)
                #pragma unroll
                for (int nt = 0; nt < 2; ++nt)
                    acc[mt][nt] = __builtin_amdgcn_mfma_f32_16x16x32_f16(wa[1][mt], bh[nt], acc[mt][nt], 0, 0, 0);

            if (tap + 1 < 9) {
                #pragma unroll
                for (int mt = 0; mt < 4; ++mt) {
                    wa[0][mt] = wn[0][mt];
                    wa[1][mt] = wn[1][mt];
                }
            }
        }
    }

    // epilogue: D[m=co: row=q*4+r][n=px: col=li]; bias + relu
    #pragma unroll
    for (int mt = 0; mt < 4; ++mt) {
        #pragma unroll
        for (int r = 0; r < 4; ++r) {
            int co = co0 + mt * 16 + q * 4 + r;
            float bv = bias[co];
            #pragma unroll
            for (int nt = 0; nt < 2; ++nt) {
                int xc = xbase + nt * 16 + li;
                float v = acc[mt][nt][r] + bv;
                mid[((size_t)(n * 512 + co) * HH + y0 + yw) * WW + xc] = v > 0.f ? v : 0.f;
            }
        }
    }
}

// ---------------- head weights -> [ci][co] (co: 0..17 score, 18..53 loc, pad 64) ----
__global__ __launch_bounds__(256) void k_htrans(const float* __restrict__ Ws,
                                                const float* __restrict__ Wl,
                                                float* __restrict__ Wt2)
{
    int i = blockIdx.x * 256 + threadIdx.x;   // 512*64
    if (i >= 512 * 64) return;
    int ci = i >> 6, co = i & 63;
    float v = 0.f;
    if (co < 18) v = Ws[co * 512 + ci];
    else if (co < 54) v = Wl[(co - 18) * 512 + ci];
    Wt2[i] = v;
}

// ---------------- 1x1 heads as GEMM: sraw[n][co64][px4096] ----------------
__global__ __launch_bounds__(256) void k_hgemm(const float* __restrict__ mid,
                                               const float* __restrict__ Wt2,
                                               float* __restrict__ sraw)
{
    __shared__ float sM[32][64];   // [ci][px]
    __shared__ float sW2[32][64];  // [ci][co]
    const int t = threadIdx.x;
    const int px0 = blockIdx.x * 64, n = blockIdx.y;
    const int tx = t & 15, ty = t >> 4;

    float acc[4][4];
    #pragma unroll
    for (int c = 0; c < 4; ++c)
        #pragma unroll
        for (int j = 0; j < 4; ++j) acc[c][j] = 0.f;

    for (int ci0 = 0; ci0 < 512; ci0 += 32) {
        __syncthreads();
        #pragma unroll
        for (int l = 0; l < 8; ++l) {
            int i = l * 256 + t;
            int ci = i >> 6, px = i & 63;
            sM[ci][px] = mid[((size_t)n * 512 + ci0 + ci) * 4096 + px0 + px];
            sW2[ci][px] = Wt2[(size_t)(ci0 + ci) * 64 + px];
        }
        __syncthreads();
        #pragma unroll
        for (int ci = 0; ci < 32; ++ci) {
            float mv[4], wv[4];
            #pragma unroll
            for (int j = 0; j < 4; ++j) mv[j] = sM[ci][tx * 4 + j];
            #pragma unroll
            for (int c = 0; c < 4; ++c) wv[c] = sW2[ci][ty * 4 + c];
            #pragma unroll
            for (int c = 0; c < 4; ++c)
                #pragma unroll
                for (int j = 0; j < 4; ++j) acc[c][j] += wv[c] * mv[j];
        }
    }
    #pragma unroll
    for (int c = 0; c < 4; ++c) {
        float4 v = make_float4(acc[c][0], acc[c][1], acc[c][2], acc[c][3]);
        *(float4*)&sraw[((size_t)n * 64 + ty * 4 + c) * 4096 + px0 + tx * 4] = v;
    }
}

// ---------------- decode: softmax, loc2bbox, clip, keys, head outputs ----------------
__global__ __launch_bounds__(256) void k_decode(const float* __restrict__ sraw,
                                                const float* __restrict__ bsc,
                                                const float* __restrict__ blc,
                                                const int* __restrict__ ph,
                                                const int* __restrict__ pw,
                                                float* __restrict__ out,
                                                float* __restrict__ boxes,
                                                u32* __restrict__ key)
{
    int p = blockIdx.x * 256 + threadIdx.x;   // 0..16383
    int n = p >> 12, pi = p & 4095;
    int y = pi >> 6, xq = pi & 63;

    const float* S = sraw + (size_t)n * 64 * 4096 + pi;
    float* o0 = out + (size_t)n * 147456;
    float* o1 = out + OFF1 + (size_t)n * 73728;
    float IHf = (float)(*ph), IWf = (float)(*pw);

    #pragma unroll
    for (int a = 0; a < 9; ++a) {
        float s0 = S[(size_t)(2 * a) * 4096] + bsc[2 * a];
        float s1 = S[(size_t)(2 * a + 1) * 4096] + bsc[2 * a + 1];
        float dy = S[(size_t)(18 + 4 * a) * 4096] + blc[4 * a];
        float dx = S[(size_t)(19 + 4 * a) * 4096] + blc[4 * a + 1];
        float dh = S[(size_t)(20 + 4 * a) * 4096] + blc[4 * a + 2];
        float dw = S[(size_t)(21 + 4 * a) * 4096] + blc[4 * a + 3];

        o1[(pi * 9 + a) * 2 + 0] = s0;
        o1[(pi * 9 + a) * 2 + 1] = s1;
        o0[(pi * 9 + a) * 4 + 0] = dy;
        o0[(pi * 9 + a) * 4 + 1] = dx;
        o0[(pi * 9 + a) * 4 + 2] = dh;
        o0[(pi * 9 + a) * 4 + 3] = dw;

        // softmax fg (max-subtracted like jax.nn.softmax)
        float mm = fmaxf(s0, s1);
        float e0 = expf(s0 - mm), e1 = expf(s1 - mm);
        float fg = e1 / (e0 + e1);

        // anchor (base in f64 like numpy, then f32 add of exact shift)
        int ri = a / 3, si = a - ri * 3;
        double s = (double)(8 << si);
        double rr = (ri == 0) ? 0.5 : ((ri == 1) ? 1.0 : 2.0);
        double hh = 16.0 * s * sqrt(rr);
        double wd = 16.0 * s * sqrt(1.0 / rr);
        float a0 = (float)(8.0 - hh * 0.5) + (float)(y * 16);
        float a1 = (float)(8.0 - wd * 0.5) + (float)(xq * 16);
        float a2 = (float)(8.0 + hh * 0.5) + (float)(y * 16);
        float a3 = (float)(8.0 + wd * 0.5) + (float)(xq * 16);

        // loc2bbox
        float h = a2 - a0, w = a3 - a1;
        float cy = a0 + 0.5f * h, cx = a1 + 0.5f * w;
        float ncy = dy * h + cy, ncx = dx * w + cx;
        float nh = expf(dh) * h, nw = expf(dw) * w;
        float b0 = fminf(fmaxf(ncy - 0.5f * nh, 0.f), IHf);
        float b1 = fminf(fmaxf(ncx - 0.5f * nw, 0.f), IWf);
        float b2 = fminf(fmaxf(ncy + 0.5f * nh, 0.f), IHf);
        float b3 = fminf(fmaxf(ncx + 0.5f * nw, 0.f), IWf);

        bool ok = (b2 - b0 >= 16.0f) && (b3 - b1 >= 16.0f);
        float sc = ok ? fg : NEGV;

        int gi = n * HWA + pi * 9 + a;
        ((float4*)boxes)[gi] = make_float4(b0, b1, b2, b3);
        u32 u = __float_as_uint(sc);
        u32 kasc = (u & 0x80000000u) ? ~u : (u | 0x80000000u);
        key[gi] = ~kasc;   // ascending key == descending score
    }
}

// ---------------- anchors out + roi_indices + zero rois ----------------
__global__ void k_misc(float* __restrict__ out)
{
    int i = blockIdx.x * 256 + threadIdx.x;
    if (i < 4800) out[OFF2 + i] = 0.f;
    if (i < 1200) out[OFF3 + i] = (float)(i / 300);
    if (i < HWA) {
        int pi = i / 9, a = i - pi * 9;
        int y = pi >> 6, xq = pi & 63;
        int ri = a / 3, si = a - ri * 3;
        double s = (double)(8 << si);
        double rr = (ri == 0) ? 0.5 : ((ri == 1) ? 1.0 : 2.0);
        double hh = 16.0 * s * sqrt(rr);
        double wd = 16.0 * s * sqrt(1.0 / rr);
        out[OFF4 + i * 4 + 0] = (float)(8.0 - hh * 0.5) + (float)(y * 16);
        out[OFF4 + i * 4 + 1] = (float)(8.0 - wd * 0.5) + (float)(xq * 16);
        out[OFF4 + i * 4 + 2] = (float)(8.0 + hh * 0.5) + (float)(y * 16);
        out[OFF4 + i * 4 + 3] = (float)(8.0 + wd * 0.5) + (float)(xq * 16);
    }
}

// ---------------- exact rank-6000 radix select + compact ----------------
__global__ __launch_bounds__(1024) void k_select(const u32* __restrict__ key,
                                                 u64* __restrict__ cmp,
                                                 int* __restrict__ nvalid)
{
    __shared__ int hist[256];
    __shared__ u32 sPref;
    __shared__ int sR;
    __shared__ int cLess, cEq, cVal;
    int n = blockIdx.x, t = threadIdx.x;
    const u32* k0 = key + (size_t)n * HWA;

    u32 pref = 0, mask = 0;
    int R = PRE_NMS;
    for (int pass = 0; pass < 4; ++pass) {
        int shift = 24 - pass * 8;
        if (t < 256) hist[t] = 0;
        __syncthreads();
        for (int i = t; i < HWA; i += 1024) {
            u32 k = k0[i];
            if ((k & mask) == pref) atomicAdd(&hist[(k >> shift) & 255], 1);
        }
        __syncthreads();
        if (t == 0) {
            int cum = 0;
            for (int b = 0; b < 256; ++b) {
                int c = hist[b];
                if (cum + c >= R) { sPref = pref | ((u32)b << shift); sR = R - cum; break; }
                cum += c;
            }
        }
        __syncthreads();
        pref = sPref; R = sR; mask |= (0xFFu << shift);
        __syncthreads();
    }
    u32 T = pref;   // exact 6000th smallest key
    if (t == 0) { cLess = 0; cEq = 0; cVal = 0; }
    __syncthreads();
    for (int i = t; i < HWA; i += 1024) {
        u32 k = k0[i];
        if (k < NEGK) atomicAdd(&cVal, 1);
        if (k < T) {
            int p = atomicAdd(&cLess, 1);
            cmp[(size_t)n * 8192 + p] = ((u64)k << 32) | (u32)i;
        } else if (k == T) {
            int p = atomicAdd(&cEq, 1);
            if (p < R) cmp[(size_t)n * 8192 + (PRE_NMS - 1 - p)] = ((u64)k << 32) | (u32)i;
        }
    }
    for (int i = PRE_NMS + t; i < 8192; i += 1024) cmp[(size_t)n * 8192 + i] = ~0ull;
    __syncthreads();
    if (t == 0) nvalid[n] = cVal < PRE_NMS ? cVal : PRE_NMS;
}

// ---------------- bitonic sort of 8192 (key<<32|idx) in LDS ----------------
__global__ __launch_bounds__(1024) void k_sort(const u64* __restrict__ cmp,
                                               const float* __restrict__ boxes,
                                               float* __restrict__ boxesS)
{
    __shared__ u64 sK[8192];   // exactly 64 KiB
    int n = blockIdx.x, t = threadIdx.x;
    for (int i = t; i < 8192; i += 1024) sK[i] = cmp[(size_t)n * 8192 + i];
    for (unsigned k = 2; k <= 8192; k <<= 1) {
        for (unsigned j = k >> 1; j > 0; j >>= 1) {
            __syncthreads();
            #pragma unroll
            for (int v = 0; v < 8; ++v) {
                int i = v * 1024 + t;
                int ixj = i ^ (int)j;
                if (ixj > i) {
                    u64 a = sK[i], b = sK[ixj];
                    bool up = ((i & (int)k) == 0);
                    if (up ? (a > b) : (a < b)) { sK[i] = b; sK[ixj] = a; }
                }
            }
        }
    }
    __syncthreads();
    const float4* bsrc = (const float4*)boxes + (size_t)n * HWA;
    float4* bdst = (float4*)boxesS + (size_t)n * PRE_NMS;
    for (int i = t; i < PRE_NMS; i += 1024) {
        u32 idx = (u32)(sK[i] & 0xFFFFFFFFu);
        bdst[i] = bsrc[idx];
    }
}

// ---------------- IoU suppression bitmask: mask[n][i][w] ----------------
__global__ __launch_bounds__(64) void k_iou(const float* __restrict__ boxesS,
                                            u64* __restrict__ mask)
{
    __shared__ float4 cb[64];
    int w = blockIdx.x, ic = blockIdx.y, n = blockIdx.z;
    int t = threadIdx.x;
    const float4* B = (const float4*)boxesS + (size_t)n * PRE_NMS;
    int jc = w * 64 + t;
    cb[t] = (jc < PRE_NMS) ? B[jc] : make_float4(0.f, 0.f, 0.f, 0.f);
    __syncthreads();
    int i = ic * 64 + t;
    if (i >= PRE_NMS) return;
    float4 bb = B[i];
    float area1 = (bb.z - bb.x) * (bb.w - bb.y);
    u64 m = 0;
    #pragma unroll 8
    for (int j = 0; j < 64; ++j) {
        float4 o = cb[j];
        float ty_ = fmaxf(bb.x, o.x), tx_ = fmaxf(bb.y, o.y);
        float by_ = fminf(bb.z, o.z), bx_ = fminf(bb.w, o.w);
        float inter = fmaxf(by_ - ty_, 0.f) * fmaxf(bx_ - tx_, 0.f);
        float area2 = (o.z - o.x) * (o.w - o.y);
        float iou = inter / (area1 + area2 - inter + 1e-9f);
        if (iou > 0.7f) m |= (1ull << j);
    }
    mask[((size_t)n * PRE_NMS + i) * NWORD + w] = m;
}

// ---------------- greedy bitmask NMS: single wave, zero barriers ----------------
__global__ __launch_bounds__(64) void k_nms3(const u64* __restrict__ mask,
                                             const int* __restrict__ nvalid,
                                             const float* __restrict__ boxesS,
                                             float* __restrict__ rois)
{
    int n = blockIdx.x, lane = threadIdx.x;
    int nv = nvalid[n];
    const u64* M = mask + (size_t)n * PRE_NMS * NWORD;
    const float4* B = (const float4*)boxesS + (size_t)n * PRE_NMS;

    auto vmask = [&](int w) -> u64 {
        int lo = w * 64;
        if (nv >= lo + 64) return ~0ull;
        if (nv <= lo) return 0ull;
        return (1ull << (nv - lo)) - 1ull;
    };
    u64 vm0 = vmask(lane);
    u64 vm1 = (lane < NWORD - 64) ? vmask(64 + lane) : 0ull;
    u64 rem0 = 0, rem1 = 0;

    int cnt = 0;
    while (cnt < POST_NMS) {
        u64 c0 = (~rem0) & vm0;
        u64 c1 = (~rem1) & vm1;
        int sel;
        u64 b0 = __ballot(c0 != 0);
        if (b0) {
            int l = __builtin_ctzll(b0);
            u64 w = __shfl(c0, l);
            sel = l * 64 + __builtin_ctzll(w);
        } else {
            u64 b1 = __ballot(c1 != 0);
            if (!b1) break;
            int l = __builtin_ctzll(b1);
            u64 w = __shfl(c1, l);
            sel = (64 + l) * 64 + __builtin_ctzll(w);
        }
        if (lane == 0) {
            float4 bb = B[sel];
            float* orow = rois + (size_t)(n * POST_NMS + cnt) * 4;
            orow[0] = bb.x; orow[1] = bb.y; orow[2] = bb.z; orow[3] = bb.w;
        }
        const u64* Mr = M + (size_t)sel * NWORD;
        rem0 |= Mr[lane];
        if (lane < NWORD - 64) rem1 |= Mr[64 + lane];
        cnt++;
    }
}

extern "C" void kernel_launch(void* const* d_in, const int* in_sizes, int n_in,
                              void* d_out, int out_size, void* d_ws, size_t ws_size,
                              hipStream_t stream)
{
    const float* x  = (const float*)d_in[0];
    const float* W1 = (const float*)d_in[1];
    const float* b1 = (const float*)d_in[2];
    const float* Ws = (const float*)d_in[3];
    const float* bs = (const float*)d_in[4];
    const float* Wl = (const float*)d_in[5];
    const float* bl = (const float*)d_in[6];
    const int* ih   = (const int*)d_in[7];
    const int* iw   = (const int*)d_in[8];
    float* out = (float*)d_out;
    char* ws = (char*)d_ws;

    // during conv:
    f16*   Wh2    = (f16*)  (ws);                 //  4,718,592 B (dead after conv)
    f16*   Wl2    = (f16*)  (ws + 4718592);       //  4,718,592 B (dead after conv)
    float* mid    = (float*)(ws + 9437184);       // 33,554,432 B (dead after hgemm)
    f16*   xh     = (f16*)  (ws + 42991616);      // 16,777,216 B (dead after conv)
    f16*   xl     = (f16*)  (ws + 59768832);      // 16,777,216 B (dead after conv)
    // after conv (reusing xh region at identical old offsets):
    float* boxes  = (float*)(ws + 42991616);      //  2,359,296 B
    u32*   key    = (u32*)  (ws + 45350912);      //    589,824 B
    u64*   cmp    = (u64*)  (ws + 45940736);      //    262,144 B
    float* boxesS = (float*)(ws + 46202880);      //    384,000 B
    int*   nval   = (int*)  (ws + 46586880);      //         16 B
    // reuse dead Wh2 region after conv:
    float* Wt2    = (float*)(ws);                 //    131,072 B [ci][co64]
    float* sraw   = (float*)(ws + 262144);        //  4,194,304 B [n][co64][px]
    // reuse dead mid region after hgemm:
    u64*   iomask = (u64*)  (ws + 9437184);       // 18,048,000 B

    k_prep_x<<<dim3(8, 64, 4), 256, 0, stream>>>(x, xh, xl);
    k_prep_w<<<1024, 256, 0, stream>>>(W1, Wh2, Wl2);
    k_conv_mfma<<<dim3(8, 32, 4), 256, 0, stream>>>(xh, xl, Wh2, Wl2, b1, mid);
    k_htrans<<<128, 256, 0, stream>>>(Ws, Wl, Wt2);
    k_hgemm<<<dim3(64, 4), 256, 0, stream>>>(mid, Wt2, sraw);
    k_decode<<<64, 256, 0, stream>>>(sraw, bs, bl, ih, iw, out, boxes, key);
    k_misc<<<144, 256, 0, stream>>>(out);
    k_select<<<4, 1024, 0, stream>>>(key, cmp, nval);
    k_sort<<<4, 1024, 0, stream>>>(cmp, boxes, boxesS);
    k_iou<<<dim3(NWORD, NWORD, NIMG), 64, 0, stream>>>(boxesS, iomask);
    k_nms3<<<NIMG, 64, 0, stream>>>(iomask, nval, boxesS, out + OFF2);
}

// Round 7
// 862.891 us; speedup vs baseline: 4.8483x; 1.3134x over previous
//
#include <hip/hip_runtime.h>
#include <math.h>

#define HH 64
#define WW 64
#define NIMG 4
#define CIN 512
#define AA 9
#define HWA (HH*WW*AA)          // 36864
#define PRE_NMS 6000
#define POST_NMS 300
#define NEGV (-1e10f)
#define NEGK 0xD01502F9u        // descending-order key of -1e10f
#define NWORD 94                // ceil(6000/64)

#define OFF1 589824             // rpn_scores
#define OFF2 884736             // rois
#define OFF3 889536             // roi_indices
#define OFF4 890736             // anchors

typedef unsigned int u32;
typedef unsigned long long u64;
typedef _Float16 f16;
typedef _Float16 half8 __attribute__((ext_vector_type(8)));
typedef float f32x4 __attribute__((ext_vector_type(4)));

__device__ __forceinline__ void gload_lds16(const void* g, void* l)
{
    __builtin_amdgcn_global_load_lds((const __attribute__((address_space(1))) void*)g,
                                     (__attribute__((address_space(3))) void*)l,
                                     16, 0, 0);
}

// ---------------- prep: x[n][ci][y][xc] f32 -> x_t[n][y][xc][ci] fp16 hi/lo ----------
__global__ __launch_bounds__(256) void k_prep_x(const float* __restrict__ x,
                                                f16* __restrict__ xh,
                                                f16* __restrict__ xl)
{
    __shared__ float tile[64][65];
    int ci0 = blockIdx.x * 64, y = blockIdx.y, n = blockIdx.z;
    int t = threadIdx.x;
    #pragma unroll
    for (int l = 0; l < 16; ++l) {
        int idx = l * 256 + t;
        int cc = idx >> 6, xc = idx & 63;
        tile[cc][xc] = x[((size_t)(n * CIN + ci0 + cc) * HH + y) * WW + xc];
    }
    __syncthreads();
    #pragma unroll
    for (int l = 0; l < 16; ++l) {
        int idx = l * 256 + t;
        int xc = idx >> 6, cc = idx & 63;
        float v = tile[cc][xc];
        f16 hi = (f16)v;
        f16 lo = (f16)(v - (float)hi);
        size_t o = ((size_t)(n * 64 + y) * 64 + xc) * 512 + ci0 + cc;
        xh[o] = hi; xl[o] = lo;
    }
}

// ---------------- prep: W1[co][ci][tap] f32 -> W2[tap][co][ci] fp16 hi/lo ----------
__global__ __launch_bounds__(256) void k_prep_w(const float* __restrict__ W1,
                                                f16* __restrict__ wh,
                                                f16* __restrict__ wl)
{
    int idx = blockIdx.x * 256 + threadIdx.x;   // 512*512
    int co = idx >> 9, ci = idx & 511;
    #pragma unroll
    for (int tap = 0; tap < 9; ++tap) {
        float v = W1[(size_t)idx * 9 + tap];
        f16 hi = (f16)v;
        f16 lo = (f16)(v - (float)hi);
        size_t o = ((size_t)tap * 512 + co) * 512 + ci;
        wh[o] = hi; wl[o] = lo;
    }
}

// ---------------- conv3x3 via MFMA fp16x3 implicit GEMM (single-buffer, 4 blk/CU) ---
// Block 256 (4 waves): out tile = 64 cout x 64 x x 2 y. Grid (8, 32, 4).
// Wave: 2 co-tiles x 2 px-tiles x 2 y = 8 16x16 tiles. LDS 32 KB single buffer.
__global__ __launch_bounds__(256, 4) void k_conv_mfma(const f16* __restrict__ xh,
                                                      const f16* __restrict__ xl,
                                                      const f16* __restrict__ wh,
                                                      const f16* __restrict__ wl,
                                                      const float* __restrict__ bias,
                                                      float* __restrict__ mid)
{
    __shared__ f16 sX[2][4][64][32];   // [plane][row y0-1..y0+2][col][ci] = 32768 B
    const int t = threadIdx.x;
    const int co0 = blockIdx.x * 64, yb = blockIdx.y, n = blockIdx.z;
    const int y0 = yb * 2;
    const int wv = t >> 6, lane = t & 63;
    const int q = lane >> 4, li = lane & 15;
    const int mh = wv & 1;             // co half (32 co)
    const int xhp = wv >> 1;           // px half (32 px)

    // pre-zero vertical-halo rows (never written by masked prefetch; zero is ci-invariant)
    if (yb == 0 || yb == 31) {
        int rowu = (yb == 0) ? 0 : 3072;           // u32 offset of row 0 / row 3
        u32* p = (u32*)&sX[0][0][0][0];
        #pragma unroll
        for (int l = 0; l < 8; ++l) {
            int idx = l * 256 + t;                 // 0..2047
            int plane = idx >> 10, r = idx & 1023;
            p[plane * 4096 + rowu + r] = 0;
        }
    }

    f32x4 acc[2][2][2];   // [mt][xn][yy]
    #pragma unroll
    for (int mt = 0; mt < 2; ++mt)
        #pragma unroll
        for (int xn = 0; xn < 2; ++xn)
            #pragma unroll
            for (int yy = 0; yy < 2; ++yy)
                acc[mt][xn][yy] = (f32x4){0.f, 0.f, 0.f, 0.f};

    // staging: 32 wave-insts x 1 KB = both planes, 4 rows, 64 cols, 32 ci
    auto prefetch = [&](int ci0) {
        #pragma unroll
        for (int m = 0; m < 8; ++m) {
            int k2 = wv * 8 + m;               // 0..31, wave-uniform
            int plane = k2 >> 4;
            int row = (k2 >> 2) & 3;
            int gy = y0 - 1 + row;
            if ((unsigned)gy < 64u) {
                int col = ((k2 & 3) << 4) + (lane >> 2);
                int s = lane & 3;
                const f16* src = (plane ? xl : xh) +
                    (((size_t)(n * 64 + gy) * 64 + col) * 512 + ci0 + s * 8);
                f16* dst = &sX[0][0][0][0] + (size_t)k2 * 512 + lane * 8;
                gload_lds16(src, dst);
            }
        }
    };

    half8 wa[2][2], wn[2][2];    // [plane][mt]
    auto loadW = [&](half8 w[2][2], int ci0, int tap) {
        #pragma unroll
        for (int mt = 0; mt < 2; ++mt) {
            size_t base = ((size_t)(tap * 512) + co0 + mh * 32 + mt * 16 + li) * 512 + ci0 + q * 8;
            w[0][mt] = *(const half8*)(wh + base);
            w[1][mt] = *(const half8*)(wl + base);
        }
    };

    prefetch(0);
    loadW(wa, 0, 0);

    const half8 zero8 = {(f16)0, (f16)0, (f16)0, (f16)0, (f16)0, (f16)0, (f16)0, (f16)0};

    for (int chunk = 0; chunk < 16; ++chunk) {
        const int ci0 = chunk * 32;
        __syncthreads();                       // data ready (vmcnt+lgkm drained)

        #pragma unroll
        for (int tap = 0; tap < 9; ++tap) {
            if (tap < 8) loadW(wn, ci0, tap + 1);
            const int ky = tap / 3, kx = tap - ky * 3;

            half8 B[2][2][2];                  // [plane][xn][yy]
            #pragma unroll
            for (int xn = 0; xn < 2; ++xn) {
                int xc = xhp * 32 + xn * 16 + li;
                int colr = xc + kx - 1;
                bool oob = (colr < 0) || (colr > 63);
                int colc = oob ? 0 : colr;
                #pragma unroll
                for (int yy = 0; yy < 2; ++yy) {
                    int row = yy + ky;
                    const f16* ph = &sX[0][row][colc][q * 8];
                    half8 vh = *(const half8*)ph;
                    half8 vl = *(const half8*)(ph + 8192);
                    if (oob) { vh = zero8; vl = zero8; }
                    B[0][xn][yy] = vh; B[1][xn][yy] = vl;
                }
            }
            #pragma unroll
            for (int mt = 0; mt < 2; ++mt)
                #pragma unroll
                for (int xn = 0; xn < 2; ++xn)
                    #pragma unroll
                    for (int yy = 0; yy < 2; ++yy)
                        acc[mt][xn][yy] = __builtin_amdgcn_mfma_f32_16x16x32_f16(wa[0][mt], B[0][xn][yy], acc[mt][xn][yy], 0, 0, 0);
            #pragma unroll
            for (int mt = 0; mt < 2; ++mt)
                #pragma unroll
                for (int xn = 0; xn < 2; ++xn)
                    #pragma unroll
                    for (int yy = 0; yy < 2; ++yy)
                        acc[mt][xn][yy] = __builtin_amdgcn_mfma_f32_16x16x32_f16(wa[0][mt], B[1][xn][yy], acc[mt][xn][yy], 0, 0, 0);
            #pragma unroll
            for (int mt = 0; mt < 2; ++mt)
                #pragma unroll
                for (int xn = 0; xn < 2; ++xn)
                    #pragma unroll
                    for (int yy = 0; yy < 2; ++yy)
                        acc[mt][xn][yy] = __builtin_amdgcn_mfma_f32_16x16x32_f16(wa[1][mt], B[0][xn][yy], acc[mt][xn][yy], 0, 0, 0);

            if (tap < 8) {
                #pragma unroll
                for (int pl = 0; pl < 2; ++pl)
                    #pragma unroll
                    for (int mt = 0; mt < 2; ++mt) wa[pl][mt] = wn[pl][mt];
            }
        }

        if (chunk + 1 < 16) {
            __syncthreads();                   // compute done, safe to overwrite sX
            prefetch(ci0 + 32);
            loadW(wa, ci0 + 32, 0);
        }
    }

    // epilogue: D row=q*4+r -> co, col=li -> px; bias + relu
    #pragma unroll
    for (int mt = 0; mt < 2; ++mt) {
        #pragma unroll
        for (int r = 0; r < 4; ++r) {
            int co = co0 + mh * 32 + mt * 16 + q * 4 + r;
            float bv = bias[co];
            #pragma unroll
            for (int xn = 0; xn < 2; ++xn) {
                int xc = xhp * 32 + xn * 16 + li;
                #pragma unroll
                for (int yy = 0; yy < 2; ++yy) {
                    float v = acc[mt][xn][yy][r] + bv;
                    mid[((size_t)(n * 512 + co) * HH + y0 + yy) * WW + xc] = v > 0.f ? v : 0.f;
                }
            }
        }
    }
}

// ---------------- head weights -> [ci][co] (co: 0..17 score, 18..53 loc, pad 64) ----
__global__ __launch_bounds__(256) void k_htrans(const float* __restrict__ Ws,
                                                const float* __restrict__ Wl,
                                                float* __restrict__ Wt2)
{
    int i = blockIdx.x * 256 + threadIdx.x;   // 512*64
    if (i >= 512 * 64) return;
    int ci = i >> 6, co = i & 63;
    float v = 0.f;
    if (co < 18) v = Ws[co * 512 + ci];
    else if (co < 54) v = Wl[(co - 18) * 512 + ci];
    Wt2[i] = v;
}

// ---------------- 1x1 heads as GEMM: sraw[n][co64][px4096] ----------------
__global__ __launch_bounds__(256) void k_hgemm(const float* __restrict__ mid,
                                               const float* __restrict__ Wt2,
                                               float* __restrict__ sraw)
{
    __shared__ float sM[32][64];   // [ci][px]
    __shared__ float sW2[32][64];  // [ci][co]
    const int t = threadIdx.x;
    const int px0 = blockIdx.x * 64, n = blockIdx.y;
    const int tx = t & 15, ty = t >> 4;

    float acc[4][4];
    #pragma unroll
    for (int c = 0; c < 4; ++c)
        #pragma unroll
        for (int j = 0; j < 4; ++j) acc[c][j] = 0.f;

    for (int ci0 = 0; ci0 < 512; ci0 += 32) {
        __syncthreads();
        #pragma unroll
        for (int l = 0; l < 8; ++l) {
            int i = l * 256 + t;
            int ci = i >> 6, px = i & 63;
            sM[ci][px] = mid[((size_t)n * 512 + ci0 + ci) * 4096 + px0 + px];
            sW2[ci][px] = Wt2[(size_t)(ci0 + ci) * 64 + px];
        }
        __syncthreads();
        #pragma unroll
        for (int ci = 0; ci < 32; ++ci) {
            float mv[4], wv[4];
            #pragma unroll
            for (int j = 0; j < 4; ++j) mv[j] = sM[ci][tx * 4 + j];
            #pragma unroll
            for (int c = 0; c < 4; ++c) wv[c] = sW2[ci][ty * 4 + c];
            #pragma unroll
            for (int c = 0; c < 4; ++c)
                #pragma unroll
                for (int j = 0; j < 4; ++j) acc[c][j] += wv[c] * mv[j];
        }
    }
    #pragma unroll
    for (int c = 0; c < 4; ++c) {
        float4 v = make_float4(acc[c][0], acc[c][1], acc[c][2], acc[c][3]);
        *(float4*)&sraw[((size_t)n * 64 + ty * 4 + c) * 4096 + px0 + tx * 4] = v;
    }
}

// ---------------- decode: softmax, loc2bbox, clip, keys, head outputs ----------------
__global__ __launch_bounds__(256) void k_decode(const float* __restrict__ sraw,
                                                const float* __restrict__ bsc,
                                                const float* __restrict__ blc,
                                                const int* __restrict__ ph,
                                                const int* __restrict__ pw,
                                                float* __restrict__ out,
                                                float* __restrict__ boxes,
                                                u32* __restrict__ key)
{
    int p = blockIdx.x * 256 + threadIdx.x;   // 0..16383
    int n = p >> 12, pi = p & 4095;
    int y = pi >> 6, xq = pi & 63;

    const float* S = sraw + (size_t)n * 64 * 4096 + pi;
    float* o0 = out + (size_t)n * 147456;
    float* o1 = out + OFF1 + (size_t)n * 73728;
    float IHf = (float)(*ph), IWf = (float)(*pw);

    #pragma unroll
    for (int a = 0; a < 9; ++a) {
        float s0 = S[(size_t)(2 * a) * 4096] + bsc[2 * a];
        float s1 = S[(size_t)(2 * a + 1) * 4096] + bsc[2 * a + 1];
        float dy = S[(size_t)(18 + 4 * a) * 4096] + blc[4 * a];
        float dx = S[(size_t)(19 + 4 * a) * 4096] + blc[4 * a + 1];
        float dh = S[(size_t)(20 + 4 * a) * 4096] + blc[4 * a + 2];
        float dw = S[(size_t)(21 + 4 * a) * 4096] + blc[4 * a + 3];

        o1[(pi * 9 + a) * 2 + 0] = s0;
        o1[(pi * 9 + a) * 2 + 1] = s1;
        o0[(pi * 9 + a) * 4 + 0] = dy;
        o0[(pi * 9 + a) * 4 + 1] = dx;
        o0[(pi * 9 + a) * 4 + 2] = dh;
        o0[(pi * 9 + a) * 4 + 3] = dw;

        // softmax fg (max-subtracted like jax.nn.softmax)
        float mm = fmaxf(s0, s1);
        float e0 = expf(s0 - mm), e1 = expf(s1 - mm);
        float fg = e1 / (e0 + e1);

        // anchor (base in f64 like numpy, then f32 add of exact shift)
        int ri = a / 3, si = a - ri * 3;
        double s = (double)(8 << si);
        double rr = (ri == 0) ? 0.5 : ((ri == 1) ? 1.0 : 2.0);
        double hh = 16.0 * s * sqrt(rr);
        double wd = 16.0 * s * sqrt(1.0 / rr);
        float a0 = (float)(8.0 - hh * 0.5) + (float)(y * 16);
        float a1 = (float)(8.0 - wd * 0.5) + (float)(xq * 16);
        float a2 = (float)(8.0 + hh * 0.5) + (float)(y * 16);
        float a3 = (float)(8.0 + wd * 0.5) + (float)(xq * 16);

        // loc2bbox
        float h = a2 - a0, w = a3 - a1;
        float cy = a0 + 0.5f * h, cx = a1 + 0.5f * w;
        float ncy = dy * h + cy, ncx = dx * w + cx;
        float nh = expf(dh) * h, nw = expf(dw) * w;
        float b0 = fminf(fmaxf(ncy - 0.5f * nh, 0.f), IHf);
        float b1 = fminf(fmaxf(ncx - 0.5f * nw, 0.f), IWf);
        float b2 = fminf(fmaxf(ncy + 0.5f * nh, 0.f), IHf);
        float b3 = fminf(fmaxf(ncx + 0.5f * nw, 0.f), IWf);

        bool ok = (b2 - b0 >= 16.0f) && (b3 - b1 >= 16.0f);
        float sc = ok ? fg : NEGV;

        int gi = n * HWA + pi * 9 + a;
        ((float4*)boxes)[gi] = make_float4(b0, b1, b2, b3);
        u32 u = __float_as_uint(sc);
        u32 kasc = (u & 0x80000000u) ? ~u : (u | 0x80000000u);
        key[gi] = ~kasc;   // ascending key == descending score
    }
}

// ---------------- anchors out + roi_indices + zero rois ----------------
__global__ void k_misc(float* __restrict__ out)
{
    int i = blockIdx.x * 256 + threadIdx.x;
    if (i < 4800) out[OFF2 + i] = 0.f;
    if (i < 1200) out[OFF3 + i] = (float)(i / 300);
    if (i < HWA) {
        int pi = i / 9, a = i - pi * 9;
        int y = pi >> 6, xq = pi & 63;
        int ri = a / 3, si = a - ri * 3;
        double s = (double)(8 << si);
        double rr = (ri == 0) ? 0.5 : ((ri == 1) ? 1.0 : 2.0);
        double hh = 16.0 * s * sqrt(rr);
        double wd = 16.0 * s * sqrt(1.0 / rr);
        out[OFF4 + i * 4 + 0] = (float)(8.0 - hh * 0.5) + (float)(y * 16);
        out[OFF4 + i * 4 + 1] = (float)(8.0 - wd * 0.5) + (float)(xq * 16);
        out[OFF4 + i * 4 + 2] = (float)(8.0 + hh * 0.5) + (float)(y * 16);
        out[OFF4 + i * 4 + 3] = (float)(8.0 + wd * 0.5) + (float)(xq * 16);
    }
}

// ---------------- exact rank-6000 radix select + compact ----------------
__global__ __launch_bounds__(1024) void k_select(const u32* __restrict__ key,
                                                 u64* __restrict__ cmp,
                                                 int* __restrict__ nvalid)
{
    __shared__ int hist[256];
    __shared__ u32 sPref;
    __shared__ int sR;
    __shared__ int cLess, cEq, cVal;
    int n = blockIdx.x, t = threadIdx.x;
    const u32* k0 = key + (size_t)n * HWA;

    u32 pref = 0, mask = 0;
    int R = PRE_NMS;
    for (int pass = 0; pass < 4; ++pass) {
        int shift = 24 - pass * 8;
        if (t < 256) hist[t] = 0;
        __syncthreads();
        for (int i = t; i < HWA; i += 1024) {
            u32 k = k0[i];
            if ((k & mask) == pref) atomicAdd(&hist[(k >> shift) & 255], 1);
        }
        __syncthreads();
        if (t == 0) {
            int cum = 0;
            for (int b = 0; b < 256; ++b) {
                int c = hist[b];
                if (cum + c >= R) { sPref = pref | ((u32)b << shift); sR = R - cum; break; }
                cum += c;
            }
        }
        __syncthreads();
        pref = sPref; R = sR; mask |= (0xFFu << shift);
        __syncthreads();
    }
    u32 T = pref;   // exact 6000th smallest key
    if (t == 0) { cLess = 0; cEq = 0; cVal = 0; }
    __syncthreads();
    for (int i = t; i < HWA; i += 1024) {
        u32 k = k0[i];
        if (k < NEGK) atomicAdd(&cVal, 1);
        if (k < T) {
            int p = atomicAdd(&cLess, 1);
            cmp[(size_t)n * 8192 + p] = ((u64)k << 32) | (u32)i;
        } else if (k == T) {
            int p = atomicAdd(&cEq, 1);
            if (p < R) cmp[(size_t)n * 8192 + (PRE_NMS - 1 - p)] = ((u64)k << 32) | (u32)i;
        }
    }
    for (int i = PRE_NMS + t; i < 8192; i += 1024) cmp[(size_t)n * 8192 + i] = ~0ull;
    __syncthreads();
    if (t == 0) nvalid[n] = cVal < PRE_NMS ? cVal : PRE_NMS;
}

// ---------------- bitonic sort of 8192 (key<<32|idx) in LDS ----------------
__global__ __launch_bounds__(1024) void k_sort(const u64* __restrict__ cmp,
                                               const float* __restrict__ boxes,
                                               float* __restrict__ boxesS)
{
    __shared__ u64 sK[8192];   // exactly 64 KiB
    int n = blockIdx.x, t = threadIdx.x;
    for (int i = t; i < 8192; i += 1024) sK[i] = cmp[(size_t)n * 8192 + i];
    for (unsigned k = 2; k <= 8192; k <<= 1) {
        for (unsigned j = k >> 1; j > 0; j >>= 1) {
            __syncthreads();
            #pragma unroll
            for (int v = 0; v < 8; ++v) {
                int i = v * 1024 + t;
                int ixj = i ^ (int)j;
                if (ixj > i) {
                    u64 a = sK[i], b = sK[ixj];
                    bool up = ((i & (int)k) == 0);
                    if (up ? (a > b) : (a < b)) { sK[i] = b; sK[ixj] = a; }
                }
            }
        }
    }
    __syncthreads();
    const float4* bsrc = (const float4*)boxes + (size_t)n * HWA;
    float4* bdst = (float4*)boxesS + (size_t)n * PRE_NMS;
    for (int i = t; i < PRE_NMS; i += 1024) {
        u32 idx = (u32)(sK[i] & 0xFFFFFFFFu);
        bdst[i] = bsrc[idx];
    }
}

// ---------------- IoU suppression bitmask: mask[n][i][w], upper triangle only ------
// Greedy selection is monotone increasing, so bits for j < sel can never matter:
// blocks with all j < all i are skipped (their mask words stay garbage, harmless).
__global__ __launch_bounds__(64) void k_iou(const float* __restrict__ boxesS,
                                            u64* __restrict__ mask)
{
    __shared__ float4 cb[64];
    int w = blockIdx.x, ic = blockIdx.y, n = blockIdx.z;
    if (w < ic) return;                       // strictly-lower triangle: unused
    int t = threadIdx.x;
    const float4* B = (const float4*)boxesS + (size_t)n * PRE_NMS;
    int jc = w * 64 + t;
    cb[t] = (jc < PRE_NMS) ? B[jc] : make_float4(0.f, 0.f, 0.f, 0.f);
    __syncthreads();
    int i = ic * 64 + t;
    if (i >= PRE_NMS) return;
    float4 bb = B[i];
    float area1 = (bb.z - bb.x) * (bb.w - bb.y);
    u64 m = 0;
    #pragma unroll 8
    for (int j = 0; j < 64; ++j) {
        float4 o = cb[j];
        float ty_ = fmaxf(bb.x, o.x), tx_ = fmaxf(bb.y, o.y);
        float by_ = fminf(bb.z, o.z), bx_ = fminf(bb.w, o.w);
        float inter = fmaxf(by_ - ty_, 0.f) * fmaxf(bx_ - tx_, 0.f);
        float area2 = (o.z - o.x) * (o.w - o.y);
        float iou = inter / (area1 + area2 - inter + 1e-9f);
        if (iou > 0.7f) m |= (1ull << j);
    }
    mask[((size_t)n * PRE_NMS + i) * NWORD + w] = m;
}

// ---------------- greedy bitmask NMS: single wave, zero barriers ----------------
__global__ __launch_bounds__(64) void k_nms3(const u64* __restrict__ mask,
                                             const int* __restrict__ nvalid,
                                             const float* __restrict__ boxesS,
                                             float* __restrict__ rois)
{
    int n = blockIdx.x, lane = threadIdx.x;
    int nv = nvalid[n];
    const u64* M = mask + (size_t)n * PRE_NMS * NWORD;
    const float4* B = (const float4*)boxesS + (size_t)n * PRE_NMS;

    auto vmask = [&](int w) -> u64 {
        int lo = w * 64;
        if (nv >= lo + 64) return ~0ull;
        if (nv <= lo) return 0ull;
        return (1ull << (nv - lo)) - 1ull;
    };
    u64 vm0 = vmask(lane);
    u64 vm1 = (lane < NWORD - 64) ? vmask(64 + lane) : 0ull;
    u64 rem0 = 0, rem1 = 0;

    int cnt = 0;
    while (cnt < POST_NMS) {
        u64 c0 = (~rem0) & vm0;
        u64 c1 = (~rem1) & vm1;
        int sel;
        u64 b0 = __ballot(c0 != 0);
        if (b0) {
            int l = __builtin_ctzll(b0);
            u64 w = __shfl(c0, l);
            sel = l * 64 + __builtin_ctzll(w);
        } else {
            u64 b1 = __ballot(c1 != 0);
            if (!b1) break;
            int l = __builtin_ctzll(b1);
            u64 w = __shfl(c1, l);
            sel = (64 + l) * 64 + __builtin_ctzll(w);
        }
        if (lane == 0) {
            float4 bb = B[sel];
            float* orow = rois + (size_t)(n * POST_NMS + cnt) * 4;
            orow[0] = bb.x; orow[1] = bb.y; orow[2] = bb.z; orow[3] = bb.w;
        }
        const u64* Mr = M + (size_t)sel * NWORD;
        rem0 |= Mr[lane];
        if (lane < NWORD - 64) rem1 |= Mr[64 + lane];
        cnt++;
    }
}

extern "C" void kernel_launch(void* const* d_in, const int* in_sizes, int n_in,
                              void* d_out, int out_size, void* d_ws, size_t ws_size,
                              hipStream_t stream)
{
    const float* x  = (const float*)d_in[0];
    const float* W1 = (const float*)d_in[1];
    const float* b1 = (const float*)d_in[2];
    const float* Ws = (const float*)d_in[3];
    const float* bs = (const float*)d_in[4];
    const float* Wl = (const float*)d_in[5];
    const float* bl = (const float*)d_in[6];
    const int* ih   = (const int*)d_in[7];
    const int* iw   = (const int*)d_in[8];
    float* out = (float*)d_out;
    char* ws = (char*)d_ws;

    // during conv:
    f16*   Wh2    = (f16*)  (ws);                 //  4,718,592 B (dead after conv)
    f16*   Wl2    = (f16*)  (ws + 4718592);       //  4,718,592 B (dead after conv)
    float* mid    = (float*)(ws + 9437184);       // 33,554,432 B (dead after hgemm)
    f16*   xh     = (f16*)  (ws + 42991616);      // 16,777,216 B (dead after conv)
    f16*   xl     = (f16*)  (ws + 59768832);      // 16,777,216 B (dead after conv)
    // after conv (reusing xh region at identical old offsets):
    float* boxes  = (float*)(ws + 42991616);      //  2,359,296 B
    u32*   key    = (u32*)  (ws + 45350912);      //    589,824 B
    u64*   cmp    = (u64*)  (ws + 45940736);      //    262,144 B
    float* boxesS = (float*)(ws + 46202880);      //    384,000 B
    int*   nval   = (int*)  (ws + 46586880);      //         16 B
    // reuse dead Wh2 region after conv:
    float* Wt2    = (float*)(ws);                 //    131,072 B [ci][co64]
    float* sraw   = (float*)(ws + 262144);        //  4,194,304 B [n][co64][px]
    // reuse dead mid region after hgemm:
    u64*   iomask = (u64*)  (ws + 9437184);       // 18,048,000 B

    k_prep_x<<<dim3(8, 64, 4), 256, 0, stream>>>(x, xh, xl);
    k_prep_w<<<1024, 256, 0, stream>>>(W1, Wh2, Wl2);
    k_conv_mfma<<<dim3(8, 32, 4), 256, 0, stream>>>(xh, xl, Wh2, Wl2, b1, mid);
    k_htrans<<<128, 256, 0, stream>>>(Ws, Wl, Wt2);
    k_hgemm<<<dim3(64, 4), 256, 0, stream>>>(mid, Wt2, sraw);
    k_decode<<<64, 256, 0, stream>>>(sraw, bs, bl, ih, iw, out, boxes, key);
    k_misc<<<144, 256, 0, stream>>>(out);
    k_select<<<4, 1024, 0, stream>>>(key, cmp, nval);
    k_sort<<<4, 1024, 0, stream>>>(cmp, boxes, boxesS);
    k_iou<<<dim3(NWORD, NWORD, NIMG), 64, 0, stream>>>(boxesS, iomask);
    k_nms3<<<NIMG, 64, 0, stream>>>(iomask, nval, boxesS, out + OFF2);
}